// Round 1
// baseline (287.373 us; speedup 1.0000x reference)
//
#include <hip/hip_runtime.h>
#include <math.h>

#define HIDDEN 1024
#define INTER  1408
#define NEXP   8
#define NTOK   2048
#define KSPLIT_LEN 704   // INTER/2

typedef short s16x8 __attribute__((ext_vector_type(8)));   // 8 bf16 MFMA operand
typedef float f32x4 __attribute__((ext_vector_type(4)));   // MFMA accumulator

static __device__ __forceinline__ short f2b(float f) {
  union { float f; unsigned u; } v; v.f = f;
  unsigned u = v.u;
  unsigned r = (u + 0x7FFFu + ((u >> 16) & 1u)) >> 16;   // RNE
  return (short)r;
}

// ---------------------------------------------------------------------------
// Router phase 1: one wave per token, fp32 exact, NO atomics.
// Writes per-token choice: ce[t] = e0 | e1<<8, cw[t] = (w0, w1).
// FUSED: also emits xb (bf16 copy of x) — the wave already holds the whole
// token row in registers, so the conversion costs 16 coalesced short-stores.
// ---------------------------------------------------------------------------
__global__ __launch_bounds__(256) void router_choice(
    const float* __restrict__ x, const float* __restrict__ rw,
    int* __restrict__ ce, float2* __restrict__ cw, short* __restrict__ xb)
{
  int wave = threadIdx.x >> 6;
  int lane = threadIdx.x & 63;
  int t = blockIdx.x * 4 + wave;
  if (t >= NTOK) return;
  const float* xt = x + (size_t)t * HIDDEN;
  float xr[16];
#pragma unroll
  for (int i = 0; i < 16; ++i) xr[i] = xt[lane + 64 * i];

  // bf16 copy of x (coalesced: 64 lanes x 2B = 128B per store instr)
  short* xo = xb + (size_t)t * HIDDEN;
#pragma unroll
  for (int i = 0; i < 16; ++i) xo[lane + 64 * i] = f2b(xr[i]);

  float logits[NEXP];
#pragma unroll
  for (int e = 0; e < NEXP; ++e) {
    const float* w = rw + e * HIDDEN;
    float acc = 0.f;
#pragma unroll
    for (int i = 0; i < 16; ++i) acc = fmaf(xr[i], w[lane + 64 * i], acc);
#pragma unroll
    for (int off = 32; off > 0; off >>= 1) acc += __shfl_xor(acc, off);
    logits[e] = acc;
  }
  if (lane == 0) {
    float mx = logits[0];
#pragma unroll
    for (int e = 1; e < NEXP; ++e) mx = fmaxf(mx, logits[e]);
    float p[NEXP];
#pragma unroll
    for (int e = 0; e < NEXP; ++e) p[e] = expf(logits[e] - mx);
    int i0 = 0;
#pragma unroll
    for (int e = 1; e < NEXP; ++e) if (p[e] > p[i0]) i0 = e;
    int i1 = (i0 == 0) ? 1 : 0;
#pragma unroll
    for (int e = 0; e < NEXP; ++e) { if (e != i0 && p[e] > p[i1]) i1 = e; }
    float denom = p[i0] + p[i1];
    ce[t] = i0 | (i1 << 8);
    cw[t] = make_float2(p[i0] / denom, p[i1] / denom);
  }
}

// ---------------------------------------------------------------------------
// Router phase 2: one block per expert. Deterministic compaction (stable in
// token order) via register histogram + LDS scan. Also computes counts[e] and
// base[e] (= sum of counts of lower-indexed experts) -> replaces prefix pass.
// ---------------------------------------------------------------------------
__global__ __launch_bounds__(256) void build_lists(
    const int* __restrict__ ce, const float2* __restrict__ cw,
    int* __restrict__ counts, int* __restrict__ base,
    int* __restrict__ tok_list, float* __restrict__ w_list)
{
  int e = blockIdx.x;          // 0..7
  int tid = threadIdx.x;       // each thread owns tokens [8*tid, 8*tid+8)
  __shared__ int hall[256][8];
  __shared__ int hsum[8];
  __shared__ int scan[256];

  int cloc[8];                 // cached choices
  int h[8] = {0,0,0,0,0,0,0,0};
  int myc = 0;
#pragma unroll
  for (int j = 0; j < 8; ++j) {
    int c = ce[tid * 8 + j];
    cloc[j] = c;
    int e0 = c & 255, e1 = (c >> 8) & 255;
    h[e0]++; h[e1]++;
    myc += (e0 == e) + (e1 == e);
  }
#pragma unroll
  for (int k = 0; k < 8; ++k) hall[tid][k] = h[k];
  scan[tid] = myc;
  __syncthreads();

  if (tid < 8) {
    int s = 0;
    for (int i = 0; i < 256; ++i) s += hall[i][tid];
    hsum[tid] = s;
  }
  // Hillis-Steele inclusive scan over per-thread counts
  int v = myc;
  for (int off = 1; off < 256; off <<= 1) {
    int prev = (tid >= off) ? scan[tid - off] : 0;
    __syncthreads();
    v = v + prev;
    scan[tid] = v;
    __syncthreads();
  }
  int pos = v - myc;           // exclusive prefix = my first slot

  if (tid == 0) {
    int b = 0;
    for (int k = 0; k < e; ++k) b += hsum[k];
    base[e] = b;
    counts[e] = hsum[e];
  }

#pragma unroll
  for (int j = 0; j < 8; ++j) {
    int t = tid * 8 + j;
    int c = cloc[j];
    int e0 = c & 255, e1 = (c >> 8) & 255;
    if (e0 == e) {
      float2 w = cw[t];
      tok_list[e * NTOK + pos] = t;                // slot 0
      w_list[e * NTOK + pos] = w.x;
      pos++;
    } else if (e1 == e) {
      float2 w = cw[t];
      tok_list[e * NTOK + pos] = t | (1 << 16);    // slot 1
      w_list[e * NTOK + pos] = w.y;
      pos++;
    }
  }
}

// ---------------------------------------------------------------------------
// Weight transpose-convert, barrier-free / LDS-free.
// One WAVE per (64-n-strip x 32-k-strip) task: lane l owns output column
// n0+l. 32 independent coalesced row-loads (256B/instr across the wave),
// register pack fp32->bf16, then 4 x dwordx4 stores = exactly one fully
// covered 64B line per lane. Latency is hidden by 32-deep per-lane load ILP
// instead of block residency (the old LDS+barrier version serialized two
// dependent phases per tiny block -> 2.2 TB/s).
// Block = 4 waves covering 4 ADJACENT k-strips of the SAME n-strip, so both
// 64B halves of each 128B line are produced by the same CU back-to-back.
//   mat 0: wg [e][1024][1408] -> wgT [e][1408][1024]
//   mat 1: wu likewise
//   mat 2: wd [e][1408][1024] -> wdT [e][1024][1408]
// Per matrix per expert: (N/64) n-strips x (K/128) k-supers = 176 blocks.
// ---------------------------------------------------------------------------
__global__ __launch_bounds__(256) void wconv(
    const float* __restrict__ wg, const float* __restrict__ wu,
    const float* __restrict__ wd,
    short* __restrict__ wgT, short* __restrict__ wuT, short* __restrict__ wdT)
{
  int id = blockIdx.x;              // 0..4223 = 3 mats * 8 e * 176
  int wave = threadIdx.x >> 6;
  int lane = threadIdx.x & 63;
  int mat = id / 1408;              // 1408 = 8 * 176
  int r = id - mat * 1408;
  int e = r / 176;
  int t = r - e * 176;

  const float* src; short* dst; int K, N;
  if (mat == 0)      { src = wg; dst = wgT; K = HIDDEN; N = INTER; }
  else if (mat == 1) { src = wu; dst = wuT; K = HIDDEN; N = INTER; }
  else               { src = wd; dst = wdT; K = INTER;  N = HIDDEN; }

  int nstr = N >> 6;                // 22 (wg/wu) or 16 (wd)
  int ks = t / nstr, nt = t - ks * nstr;
  int n0 = nt * 64;
  int k0 = ks * 128 + wave * 32;    // 4 adjacent k-strips per block

  const float* se = src + (size_t)e * (HIDDEN * INTER);
  short*       de = dst + (size_t)e * (HIDDEN * INTER);
  int n = n0 + lane;

  float v[32];
#pragma unroll
  for (int j = 0; j < 32; ++j) v[j] = se[(size_t)(k0 + j) * N + n];

  unsigned pk[16];
#pragma unroll
  for (int j = 0; j < 16; ++j) {
    unsigned lo = (unsigned short)f2b(v[2 * j]);
    unsigned hi = (unsigned short)f2b(v[2 * j + 1]);
    pk[j] = lo | (hi << 16);
  }

  short* dp = de + (size_t)n * K + k0;   // 64B-aligned (k0 % 32 == 0)
#pragma unroll
  for (int c = 0; c < 4; ++c) {
    uint4 o = make_uint4(pk[4 * c], pk[4 * c + 1], pk[4 * c + 2], pk[4 * c + 3]);
    *(uint4*)(dp + 8 * c) = o;
  }
}

// ---------------------------------------------------------------------------
// Staging geometry (both GEMMs), XOR-swizzled LDS [row][4 chunks]:
//   phys chunk p of row r holds logical chunk p ^ ((r>>1)&3); fragment read
//   (lane ml, quad q) uses phys q ^ ((ml>>1)&3) -> 2-way aliasing only (free).
//   Measured 0 LDS bank conflicts (r3/r4).
// ---------------------------------------------------------------------------

// ---------------------------------------------------------------------------
// Phase A: H = silu(X@Wg)*(X@Wu). Tile M=128 N=128 BK=32, 4 waves (2x2),
// 4x4 MFMAs each for gate AND up; register prefetch issued after the
// LDS-ready barrier. XCD-swizzled flat grid for weight-strip L2 locality.
// ---------------------------------------------------------------------------
__global__ __launch_bounds__(256, 2) void gateup_mfma(
    const short* __restrict__ xb, const short* __restrict__ wgT,
    const short* __restrict__ wuT,
    const int* __restrict__ counts, const int* __restrict__ base,
    const int* __restrict__ tok_list, short* __restrict__ hbuf)
{
  // grid = 8 xcd * 16 m * 11 g-hi = 1408; g = (e,n) in 0..87
  int id = blockIdx.x;
  int xcd = id & 7;
  int rest = id >> 3;
  int mslot = rest & 15;
  int g = (rest >> 4) * 8 + xcd;
  int e = g / 11;
  int n0 = (g - e * 11) * 128;
  int cnt = counts[e];
  int m0 = mslot * 128;
  if (m0 >= cnt) return;

  __shared__ short As[128 * 32];
  __shared__ short Bg[128 * 32];
  __shared__ short Bu[128 * 32];
  __shared__ int toks[128];

  int tid = threadIdx.x;
  if (tid < 128) {
    int r = m0 + tid;
    toks[tid] = tok_list[e * NTOK + (r < cnt ? r : cnt - 1)] & 0xFFFF;
  }
  __syncthreads();

  int sr = tid >> 1;             // 0..127
  int h = tid & 1;
  int key = (sr >> 1) & 3;
  int pair = ((2 * h) ^ key) >> 1;           // which 32B global block
  int sw = (key & 1) * 8;                    // swap c0/c1 on write
  const short* gA = xb + (size_t)toks[sr] * HIDDEN + pair * 16;
  const short* gG = wgT + ((size_t)e * INTER + n0 + sr) * HIDDEN + pair * 16;
  const short* gU = wuT + ((size_t)e * INTER + n0 + sr) * HIDDEN + pair * 16;
  short* wA0 = &As[sr * 32 + h * 16 + sw];
  short* wA1 = &As[sr * 32 + h * 16 + (8 - sw)];
  short* wG0 = &Bg[sr * 32 + h * 16 + sw];
  short* wG1 = &Bg[sr * 32 + h * 16 + (8 - sw)];
  short* wU0 = &Bu[sr * 32 + h * 16 + sw];
  short* wU1 = &Bu[sr * 32 + h * 16 + (8 - sw)];

  int wv = tid >> 6, lane = tid & 63;
  int wm = wv & 1, wn = wv >> 1;
  int q = lane >> 4, ml = lane & 15;
  int chk = q ^ ((ml >> 1) & 3);
  const short* ard = &As[(wm * 64 + ml) * 32 + chk * 8];
  const short* grd = &Bg[(wn * 64 + ml) * 32 + chk * 8];
  const short* urd = &Bu[(wn * 64 + ml) * 32 + chk * 8];

  f32x4 accg[4][4], accu[4][4];
#pragma unroll
  for (int i = 0; i < 4; ++i)
#pragma unroll
    for (int j = 0; j < 4; ++j) { accg[i][j] = (f32x4)0.f; accu[i][j] = (f32x4)0.f; }

  s16x8 a0 = *(const s16x8*)(gA);     s16x8 a1 = *(const s16x8*)(gA + 8);
  s16x8 g0 = *(const s16x8*)(gG);     s16x8 g1 = *(const s16x8*)(gG + 8);
  s16x8 u0 = *(const s16x8*)(gU);     s16x8 u1 = *(const s16x8*)(gU + 8);

  for (int k0 = 0; k0 < HIDDEN; k0 += 32) {
    __syncthreads();
    *(s16x8*)wA0 = a0; *(s16x8*)wA1 = a1;
    *(s16x8*)wG0 = g0; *(s16x8*)wG1 = g1;
    *(s16x8*)wU0 = u0; *(s16x8*)wU1 = u1;
    __syncthreads();

    int kn = (k0 + 32) & (HIDDEN - 1);
    a0 = *(const s16x8*)(gA + kn);     a1 = *(const s16x8*)(gA + kn + 8);
    g0 = *(const s16x8*)(gG + kn);     g1 = *(const s16x8*)(gG + kn + 8);
    u0 = *(const s16x8*)(gU + kn);     u1 = *(const s16x8*)(gU + kn + 8);

    s16x8 af[4], gf[4], uf[4];
#pragma unroll
    for (int i = 0; i < 4; ++i) af[i] = *(const s16x8*)(ard + i * 16 * 32);
#pragma unroll
    for (int j = 0; j < 4; ++j) {
      gf[j] = *(const s16x8*)(grd + j * 16 * 32);
      uf[j] = *(const s16x8*)(urd + j * 16 * 32);
    }
#pragma unroll
    for (int i = 0; i < 4; ++i)
#pragma unroll
      for (int j = 0; j < 4; ++j) {
        accg[i][j] = __builtin_amdgcn_mfma_f32_16x16x32_bf16(af[i], gf[j], accg[i][j], 0, 0, 0);
        accu[i][j] = __builtin_amdgcn_mfma_f32_16x16x32_bf16(af[i], uf[j], accu[i][j], 0, 0, 0);
      }
  }

  int hb = base[e];
#pragma unroll
  for (int i = 0; i < 4; ++i)
#pragma unroll
    for (int ii = 0; ii < 4; ++ii) {
      int r = m0 + wm * 64 + i * 16 + q * 4 + ii;
      if (r < cnt) {
        short* hp = hbuf + (size_t)(hb + r) * INTER + n0 + wn * 64 + ml;
#pragma unroll
        for (int j = 0; j < 4; ++j) {
          float gg = accg[i][j][ii], uu = accu[i][j][ii];
          float hh = (gg / (1.f + __expf(-gg))) * uu;
          hp[j * 16] = f2b(hh);
        }
      }
    }
}

// ---------------------------------------------------------------------------
// Phase B: Y = H @ Wd, K-split x2; scaled partials to ybuf[slot*2+ks][token]
// with plain stores (no atomics).
// ---------------------------------------------------------------------------
__global__ __launch_bounds__(256, 3) void down_mfma(
    const short* __restrict__ hbuf, const short* __restrict__ wdT,
    const int* __restrict__ counts, const int* __restrict__ base,
    const int* __restrict__ tok_list, const float* __restrict__ w_list,
    float* __restrict__ ybuf)
{
  // grid = 8 xcd * 16 m * 16 g-hi = 2048; g = (e,ks,n) in 0..127
  int id = blockIdx.x;
  int xcd = id & 7;
  int rest = id >> 3;
  int mslot = rest & 15;
  int g = (rest >> 4) * 8 + xcd;
  int e = g >> 4;
  int ks = (g >> 3) & 1;
  int n0 = (g & 7) * 128;
  int cnt = counts[e];
  int m0 = mslot * 128;
  if (m0 >= cnt) return;

  __shared__ short As[128 * 32];
  __shared__ short Bs[128 * 32];

  int tid = threadIdx.x;
  int hb = base[e];
  int kbeg = ks * KSPLIT_LEN, kend = kbeg + KSPLIT_LEN;

  int sr = tid >> 1;
  int h = tid & 1;
  int key = (sr >> 1) & 3;
  int pair = ((2 * h) ^ key) >> 1;
  int sw = (key & 1) * 8;
  int ra = m0 + sr; if (ra >= cnt) ra = cnt - 1;
  const short* gA = hbuf + (size_t)(hb + ra) * INTER + pair * 16;
  const short* gB = wdT + ((size_t)e * HIDDEN + n0 + sr) * INTER + pair * 16;
  short* wA0 = &As[sr * 32 + h * 16 + sw];
  short* wA1 = &As[sr * 32 + h * 16 + (8 - sw)];
  short* wB0 = &Bs[sr * 32 + h * 16 + sw];
  short* wB1 = &Bs[sr * 32 + h * 16 + (8 - sw)];

  int wv = tid >> 6, lane = tid & 63;
  int wm = wv & 1, wn = wv >> 1;
  int q = lane >> 4, ml = lane & 15;
  int chk = q ^ ((ml >> 1) & 3);
  const short* ard = &As[(wm * 64 + ml) * 32 + chk * 8];
  const short* brd = &Bs[(wn * 64 + ml) * 32 + chk * 8];

  f32x4 acc[4][4];
#pragma unroll
  for (int i = 0; i < 4; ++i)
#pragma unroll
    for (int j = 0; j < 4; ++j) acc[i][j] = (f32x4)0.f;

  s16x8 a0 = *(const s16x8*)(gA + kbeg);  s16x8 a1 = *(const s16x8*)(gA + kbeg + 8);
  s16x8 b0 = *(const s16x8*)(gB + kbeg);  s16x8 b1 = *(const s16x8*)(gB + kbeg + 8);

  for (int k0 = kbeg; k0 < kend; k0 += 32) {
    __syncthreads();
    *(s16x8*)wA0 = a0; *(s16x8*)wA1 = a1;
    *(s16x8*)wB0 = b0; *(s16x8*)wB1 = b1;
    __syncthreads();

    int kn = k0 + 32; if (kn >= kend) kn = kbeg;
    a0 = *(const s16x8*)(gA + kn);  a1 = *(const s16x8*)(gA + kn + 8);
    b0 = *(const s16x8*)(gB + kn);  b1 = *(const s16x8*)(gB + kn + 8);

    s16x8 af[4], bf[4];
#pragma unroll
    for (int i = 0; i < 4; ++i) af[i] = *(const s16x8*)(ard + i * 16 * 32);
#pragma unroll
    for (int j = 0; j < 4; ++j) bf[j] = *(const s16x8*)(brd + j * 16 * 32);
#pragma unroll
    for (int i = 0; i < 4; ++i)
#pragma unroll
      for (int j = 0; j < 4; ++j)
        acc[i][j] = __builtin_amdgcn_mfma_f32_16x16x32_bf16(af[i], bf[j], acc[i][j], 0, 0, 0);
  }

#pragma unroll
  for (int i = 0; i < 4; ++i)
#pragma unroll
    for (int ii = 0; ii < 4; ++ii) {
      int r = m0 + wm * 64 + i * 16 + q * 4 + ii;
      if (r < cnt) {
        int ent = tok_list[e * NTOK + r];
        int tok = ent & 0xFFFF, slot = ent >> 16;
        float wgt = w_list[e * NTOK + r];
        float* yp = ybuf + ((size_t)(slot * 2 + ks) * NTOK + tok) * HIDDEN
                    + n0 + wn * 64 + ml;
#pragma unroll
        for (int j = 0; j < 4; ++j)
          yp[j * 16] = acc[i][j][ii] * wgt;
      }
    }
}

// ---------------------------------------------------------------------------
// out = sum of 4 ybuf slabs (every element written -> no out memset needed)
// ---------------------------------------------------------------------------
__global__ __launch_bounds__(256) void combine_kernel(
    const float* __restrict__ ybuf, float* __restrict__ out)
{
  size_t i = (size_t)blockIdx.x * 256 + threadIdx.x;
  const size_t S = (size_t)NTOK * HIDDEN / 4;
  float4 a = ((const float4*)ybuf)[i];
  float4 b = ((const float4*)ybuf)[i + S];
  float4 c = ((const float4*)ybuf)[i + 2 * S];
  float4 d = ((const float4*)ybuf)[i + 3 * S];
  float4 o;
  o.x = (a.x + b.x) + (c.x + d.x);
  o.y = (a.y + b.y) + (c.y + d.y);
  o.z = (a.z + b.z) + (c.z + d.z);
  o.w = (a.w + b.w) + (c.w + d.w);
  ((float4*)out)[i] = o;
}

// ---------------------------------------------------------------------------
// ws layout (bytes):
//   0..32           counts[8]
//   32..64          base[8]
//   64..65600       tok_list[8][2048]  (token | slot<<16)
//   65600..131136   w_list[8][2048]
//   131136..139328  ce[2048]
//   139328..155712  cw[2048] float2
//   155712          xb   bf16 [2048][1024]      (4 MB)
//   +4 MB           wgT  bf16 [8][1408][1024]   (23.07 MB) } ybuf[4] (32 MB
//   +23.07 MB       wuT  bf16 [8][1408][1024]   (23.07 MB) } fp32) aliases
//                                                          } wgT+wuT after
//                                                          } gateup completes
//   +23.07 MB       wdT  bf16 [8][1024][1408]
//   +23.07 MB       hbuf bf16 [4096][1408]      (11.5 MB)
//   total ~85.2 MB
// ---------------------------------------------------------------------------
extern "C" void kernel_launch(void* const* d_in, const int* in_sizes, int n_in,
                              void* d_out, int out_size, void* d_ws, size_t ws_size,
                              hipStream_t stream)
{
  const float* x  = (const float*)d_in[0];
  const float* rw = (const float*)d_in[1];
  const float* wg = (const float*)d_in[2];
  const float* wu = (const float*)d_in[3];
  const float* wd = (const float*)d_in[4];
  float* out = (float*)d_out;

  char* ws = (char*)d_ws;
  int*    counts   = (int*)(ws);
  int*    base     = (int*)(ws + 32);
  int*    tok_list = (int*)(ws + 64);
  float*  w_list   = (float*)(ws + 64 + NEXP * NTOK * 4);
  size_t off = 64 + 2 * (size_t)NEXP * NTOK * 4;
  int*    ce = (int*)(ws + off);     off += NTOK * 4;
  float2* cw = (float2*)(ws + off);  off += NTOK * 8;
  short* xb  = (short*)(ws + off);  off += (size_t)NTOK * HIDDEN * 2;
  short* wgT = (short*)(ws + off);  off += (size_t)NEXP * HIDDEN * INTER * 2;
  short* wuT = (short*)(ws + off);  off += (size_t)NEXP * HIDDEN * INTER * 2;
  short* wdT = (short*)(ws + off);  off += (size_t)NEXP * HIDDEN * INTER * 2;
  short* hbuf = (short*)(ws + off);
  float* ybuf = (float*)wgT;   // wgT+wuT dead after gateup; 32 MB fits in 46 MB

  router_choice<<<NTOK / 4, 256, 0, stream>>>(x, rw, ce, cw, xb);
  build_lists<<<NEXP, 256, 0, stream>>>(ce, cw, counts, base, tok_list, w_list);

  wconv<<<3 * NEXP * 176, 256, 0, stream>>>(wg, wu, wd, wgT, wuT, wdT);

  gateup_mfma<<<8 * 16 * 11, 256, 0, stream>>>(xb, wgT, wuT, counts, base, tok_list, hbuf);
  down_mfma<<<8 * 16 * 16, 256, 0, stream>>>(hbuf, wdT, counts, base, tok_list, w_list, ybuf);

  combine_kernel<<<(NTOK * HIDDEN / 4) / 256, 256, 0, stream>>>(ybuf, out);
}

// Round 2
// 269.779 us; speedup vs baseline: 1.0652x; 1.0652x over previous
//
#include <hip/hip_runtime.h>
#include <math.h>

#define HIDDEN 1024
#define INTER  1408
#define NEXP   8
#define NTOK   2048
#define KSPLIT_LEN 704   // INTER/2

typedef short s16x8 __attribute__((ext_vector_type(8)));   // 8 bf16 MFMA operand
typedef float f32x4 __attribute__((ext_vector_type(4)));   // MFMA accumulator

static __device__ __forceinline__ short f2b(float f) {
  union { float f; unsigned u; } v; v.f = f;
  unsigned u = v.u;
  unsigned r = (u + 0x7FFFu + ((u >> 16) & 1u)) >> 16;   // RNE
  return (short)r;
}

// ---------------------------------------------------------------------------
// Transposed-weight layout (chunk-slab form), chosen so the TRANSPOSE writes
// are perfectly sequential:
//   wT[e][kb][kc][n][8]  (bf16), kb = k/32, kc = (k%32)/8, n = output column.
// A (n, 32k) "row" of the old layout = 4 chunks of 16B at slab stride N*16B.
// GEMM staging reads chunk c of row n at elem offset ((kb*4+c)*N + n)*8.
// ---------------------------------------------------------------------------

// ---------------------------------------------------------------------------
// Router phase 1: one wave per token, fp32 exact, NO atomics.
// Writes per-token choice: ce[t] = e0 | e1<<8, cw[t] = (w0, w1).
// FUSED: also emits xb (bf16 copy of x) — the wave already holds the whole
// token row in registers, so the conversion costs 16 coalesced short-stores.
// ---------------------------------------------------------------------------
__global__ __launch_bounds__(256) void router_choice(
    const float* __restrict__ x, const float* __restrict__ rw,
    int* __restrict__ ce, float2* __restrict__ cw, short* __restrict__ xb)
{
  int wave = threadIdx.x >> 6;
  int lane = threadIdx.x & 63;
  int t = blockIdx.x * 4 + wave;
  if (t >= NTOK) return;
  const float* xt = x + (size_t)t * HIDDEN;
  float xr[16];
#pragma unroll
  for (int i = 0; i < 16; ++i) xr[i] = xt[lane + 64 * i];

  // bf16 copy of x (coalesced: 64 lanes x 2B = 128B per store instr)
  short* xo = xb + (size_t)t * HIDDEN;
#pragma unroll
  for (int i = 0; i < 16; ++i) xo[lane + 64 * i] = f2b(xr[i]);

  float logits[NEXP];
#pragma unroll
  for (int e = 0; e < NEXP; ++e) {
    const float* w = rw + e * HIDDEN;
    float acc = 0.f;
#pragma unroll
    for (int i = 0; i < 16; ++i) acc = fmaf(xr[i], w[lane + 64 * i], acc);
#pragma unroll
    for (int off = 32; off > 0; off >>= 1) acc += __shfl_xor(acc, off);
    logits[e] = acc;
  }
  if (lane == 0) {
    float mx = logits[0];
#pragma unroll
    for (int e = 1; e < NEXP; ++e) mx = fmaxf(mx, logits[e]);
    float p[NEXP];
#pragma unroll
    for (int e = 0; e < NEXP; ++e) p[e] = expf(logits[e] - mx);
    int i0 = 0;
#pragma unroll
    for (int e = 1; e < NEXP; ++e) if (p[e] > p[i0]) i0 = e;
    int i1 = (i0 == 0) ? 1 : 0;
#pragma unroll
    for (int e = 0; e < NEXP; ++e) { if (e != i0 && p[e] > p[i1]) i1 = e; }
    float denom = p[i0] + p[i1];
    ce[t] = i0 | (i1 << 8);
    cw[t] = make_float2(p[i0] / denom, p[i1] / denom);
  }
}

// ---------------------------------------------------------------------------
// Router phase 2: one block per expert. Deterministic compaction (stable in
// token order) via register histogram + LDS scan. Also computes counts[e] and
// base[e] (= sum of counts of lower-indexed experts) -> replaces prefix pass.
// ---------------------------------------------------------------------------
__global__ __launch_bounds__(256) void build_lists(
    const int* __restrict__ ce, const float2* __restrict__ cw,
    int* __restrict__ counts, int* __restrict__ base,
    int* __restrict__ tok_list, float* __restrict__ w_list)
{
  int e = blockIdx.x;          // 0..7
  int tid = threadIdx.x;       // each thread owns tokens [8*tid, 8*tid+8)
  __shared__ int hall[256][8];
  __shared__ int hsum[8];
  __shared__ int scan[256];

  int cloc[8];                 // cached choices
  int h[8] = {0,0,0,0,0,0,0,0};
  int myc = 0;
#pragma unroll
  for (int j = 0; j < 8; ++j) {
    int c = ce[tid * 8 + j];
    cloc[j] = c;
    int e0 = c & 255, e1 = (c >> 8) & 255;
    h[e0]++; h[e1]++;
    myc += (e0 == e) + (e1 == e);
  }
#pragma unroll
  for (int k = 0; k < 8; ++k) hall[tid][k] = h[k];
  scan[tid] = myc;
  __syncthreads();

  if (tid < 8) {
    int s = 0;
    for (int i = 0; i < 256; ++i) s += hall[i][tid];
    hsum[tid] = s;
  }
  // Hillis-Steele inclusive scan over per-thread counts
  int v = myc;
  for (int off = 1; off < 256; off <<= 1) {
    int prev = (tid >= off) ? scan[tid - off] : 0;
    __syncthreads();
    v = v + prev;
    scan[tid] = v;
    __syncthreads();
  }
  int pos = v - myc;           // exclusive prefix = my first slot

  if (tid == 0) {
    int b = 0;
    for (int k = 0; k < e; ++k) b += hsum[k];
    base[e] = b;
    counts[e] = hsum[e];
  }

#pragma unroll
  for (int j = 0; j < 8; ++j) {
    int t = tid * 8 + j;
    int c = cloc[j];
    int e0 = c & 255, e1 = (c >> 8) & 255;
    if (e0 == e) {
      float2 w = cw[t];
      tok_list[e * NTOK + pos] = t;                // slot 0
      w_list[e * NTOK + pos] = w.x;
      pos++;
    } else if (e1 == e) {
      float2 w = cw[t];
      tok_list[e * NTOK + pos] = t | (1 << 16);    // slot 1
      w_list[e * NTOK + pos] = w.y;
      pos++;
    }
  }
}

// ---------------------------------------------------------------------------
// Weight transpose-convert into chunk-slab layout. Barrier-free / LDS-free.
// One WAVE per (64-n x 32-k) tile: lane l owns column n0+l; 32 coalesced
// row-loads (256B/instr across the wave), pack fp32->bf16, then 4 stores —
// store kc: 64 lanes write 64 CONSECUTIVE 16B chunks = 1KB fully-covered
// sequential per instruction (the r1 version wrote 16B/lane at 2048B lane
// stride -> 64 partial-line touches/instr -> 1.87 TB/s; this is the A/B fix).
//   mat 0: wg [e][1024][1408] -> wgT slabs (N=1408, kb=32)
//   mat 1: wu likewise
//   mat 2: wd [e][1408][1024] -> wdT slabs (N=1024, kb=44)
// 704 waves per (mat, e); 16896 waves total = 4224 blocks.
// ---------------------------------------------------------------------------
__global__ __launch_bounds__(256) void wconv(
    const float* __restrict__ wg, const float* __restrict__ wu,
    const float* __restrict__ wd,
    short* __restrict__ wgT, short* __restrict__ wuT, short* __restrict__ wdT)
{
  int gw = blockIdx.x * 4 + (threadIdx.x >> 6);   // global wave id 0..16895
  int lane = threadIdx.x & 63;
  int mat = gw / 5632;              // 5632 = 8 experts * 704 waves
  int r = gw - mat * 5632;
  int e = r / 704;
  int t = r - e * 704;

  const float* src; short* dst; int N, nstr;
  if (mat == 0)      { src = wg; dst = wgT; N = INTER;  nstr = 22; }
  else if (mat == 1) { src = wu; dst = wuT; N = INTER;  nstr = 22; }
  else               { src = wd; dst = wdT; N = HIDDEN; nstr = 16; }

  int kb = t / nstr, nt = t - kb * nstr;
  int n = nt * 64 + lane;

  const float* se = src + (size_t)e * (HIDDEN * INTER)
                        + (size_t)(kb * 32) * N + n;
  short* de = dst + (size_t)e * (HIDDEN * INTER);

  float v[32];
#pragma unroll
  for (int j = 0; j < 32; ++j) v[j] = se[(size_t)j * N];

#pragma unroll
  for (int kc = 0; kc < 4; ++kc) {
    unsigned pk[4];
#pragma unroll
    for (int m = 0; m < 4; ++m) {
      unsigned lo = (unsigned short)f2b(v[8 * kc + 2 * m]);
      unsigned hi = (unsigned short)f2b(v[8 * kc + 2 * m + 1]);
      pk[m] = lo | (hi << 16);
    }
    // slab (kb*4+kc), chunk n: elem offset ((kb*4+kc)*N + n)*8
    *(uint4*)(de + ((size_t)(kb * 4 + kc) * N + n) * 8) =
        make_uint4(pk[0], pk[1], pk[2], pk[3]);
  }
}

// ---------------------------------------------------------------------------
// Staging geometry (both GEMMs), XOR-swizzled LDS [row][4 chunks]:
//   phys chunk p of row r holds logical chunk p ^ ((r>>1)&3); fragment read
//   (lane ml, quad q) uses phys q ^ ((ml>>1)&3) -> 2-way aliasing only (free).
//   Measured 0 LDS bank conflicts. Global B-source is now the chunk-slab
//   layout: logical chunk c of row n at ((kb*4+c)*N + n)*8 elems.
// ---------------------------------------------------------------------------

// ---------------------------------------------------------------------------
// Phase A: H = silu(X@Wg)*(X@Wu). Tile M=128 N=128 BK=32, 4 waves (2x2),
// 4x4 MFMAs each for gate AND up; register prefetch issued after the
// LDS-ready barrier. XCD-swizzled flat grid for weight-strip L2 locality.
// ---------------------------------------------------------------------------
__global__ __launch_bounds__(256, 2) void gateup_mfma(
    const short* __restrict__ xb, const short* __restrict__ wgT,
    const short* __restrict__ wuT,
    const int* __restrict__ counts, const int* __restrict__ base,
    const int* __restrict__ tok_list, short* __restrict__ hbuf)
{
  // grid = 8 xcd * 16 m * 11 g-hi = 1408; g = (e,n) in 0..87
  int id = blockIdx.x;
  int xcd = id & 7;
  int rest = id >> 3;
  int mslot = rest & 15;
  int g = (rest >> 4) * 8 + xcd;
  int e = g / 11;
  int n0 = (g - e * 11) * 128;
  int cnt = counts[e];
  int m0 = mslot * 128;
  if (m0 >= cnt) return;

  __shared__ short As[128 * 32];
  __shared__ short Bg[128 * 32];
  __shared__ short Bu[128 * 32];
  __shared__ int toks[128];

  int tid = threadIdx.x;
  if (tid < 128) {
    int r = m0 + tid;
    toks[tid] = tok_list[e * NTOK + (r < cnt ? r : cnt - 1)] & 0xFFFF;
  }
  __syncthreads();

  int sr = tid >> 1;             // 0..127
  int h = tid & 1;
  int key = (sr >> 1) & 3;
  int pair = ((2 * h) ^ key) >> 1;           // which 32B global block
  int sw = (key & 1) * 8;                    // swap c0/c1 on write
  const short* gA = xb + (size_t)toks[sr] * HIDDEN + pair * 16;
  // chunk-slab B base: logical chunk c0 = 2*pair of row n0+sr
  size_t ebase = (size_t)e * (HIDDEN * INTER);
  size_t boff = (size_t)(2 * pair) * (INTER * 8) + (size_t)(n0 + sr) * 8;
  const short* gGb = wgT + ebase + boff;
  const short* gUb = wuT + ebase + boff;
  short* wA0 = &As[sr * 32 + h * 16 + sw];
  short* wA1 = &As[sr * 32 + h * 16 + (8 - sw)];
  short* wG0 = &Bg[sr * 32 + h * 16 + sw];
  short* wG1 = &Bg[sr * 32 + h * 16 + (8 - sw)];
  short* wU0 = &Bu[sr * 32 + h * 16 + sw];
  short* wU1 = &Bu[sr * 32 + h * 16 + (8 - sw)];

  int wv = tid >> 6, lane = tid & 63;
  int wm = wv & 1, wn = wv >> 1;
  int q = lane >> 4, ml = lane & 15;
  int chk = q ^ ((ml >> 1) & 3);
  const short* ard = &As[(wm * 64 + ml) * 32 + chk * 8];
  const short* grd = &Bg[(wn * 64 + ml) * 32 + chk * 8];
  const short* urd = &Bu[(wn * 64 + ml) * 32 + chk * 8];

  f32x4 accg[4][4], accu[4][4];
#pragma unroll
  for (int i = 0; i < 4; ++i)
#pragma unroll
    for (int j = 0; j < 4; ++j) { accg[i][j] = (f32x4)0.f; accu[i][j] = (f32x4)0.f; }

  s16x8 a0 = *(const s16x8*)(gA);     s16x8 a1 = *(const s16x8*)(gA + 8);
  s16x8 g0 = *(const s16x8*)(gGb);    s16x8 g1 = *(const s16x8*)(gGb + INTER * 8);
  s16x8 u0 = *(const s16x8*)(gUb);    s16x8 u1 = *(const s16x8*)(gUb + INTER * 8);

  for (int k0 = 0; k0 < HIDDEN; k0 += 32) {
    __syncthreads();
    *(s16x8*)wA0 = a0; *(s16x8*)wA1 = a1;
    *(s16x8*)wG0 = g0; *(s16x8*)wG1 = g1;
    *(s16x8*)wU0 = u0; *(s16x8*)wU1 = u1;
    __syncthreads();

    int kn = (k0 + 32) & (HIDDEN - 1);
    size_t kboff = (size_t)(kn >> 5) * (4 * INTER * 8);
    a0 = *(const s16x8*)(gA + kn);         a1 = *(const s16x8*)(gA + kn + 8);
    g0 = *(const s16x8*)(gGb + kboff);     g1 = *(const s16x8*)(gGb + kboff + INTER * 8);
    u0 = *(const s16x8*)(gUb + kboff);     u1 = *(const s16x8*)(gUb + kboff + INTER * 8);

    s16x8 af[4], gf[4], uf[4];
#pragma unroll
    for (int i = 0; i < 4; ++i) af[i] = *(const s16x8*)(ard + i * 16 * 32);
#pragma unroll
    for (int j = 0; j < 4; ++j) {
      gf[j] = *(const s16x8*)(grd + j * 16 * 32);
      uf[j] = *(const s16x8*)(urd + j * 16 * 32);
    }
#pragma unroll
    for (int i = 0; i < 4; ++i)
#pragma unroll
      for (int j = 0; j < 4; ++j) {
        accg[i][j] = __builtin_amdgcn_mfma_f32_16x16x32_bf16(af[i], gf[j], accg[i][j], 0, 0, 0);
        accu[i][j] = __builtin_amdgcn_mfma_f32_16x16x32_bf16(af[i], uf[j], accu[i][j], 0, 0, 0);
      }
  }

  int hb = base[e];
#pragma unroll
  for (int i = 0; i < 4; ++i)
#pragma unroll
    for (int ii = 0; ii < 4; ++ii) {
      int r = m0 + wm * 64 + i * 16 + q * 4 + ii;
      if (r < cnt) {
        short* hp = hbuf + (size_t)(hb + r) * INTER + n0 + wn * 64 + ml;
#pragma unroll
        for (int j = 0; j < 4; ++j) {
          float gg = accg[i][j][ii], uu = accu[i][j][ii];
          float hh = (gg / (1.f + __expf(-gg))) * uu;
          hp[j * 16] = f2b(hh);
        }
      }
    }
}

// ---------------------------------------------------------------------------
// Phase B: Y = H @ Wd, K-split x2; scaled partials to ybuf[slot*2+ks][token]
// with plain stores (no atomics).
// ---------------------------------------------------------------------------
__global__ __launch_bounds__(256, 3) void down_mfma(
    const short* __restrict__ hbuf, const short* __restrict__ wdT,
    const int* __restrict__ counts, const int* __restrict__ base,
    const int* __restrict__ tok_list, const float* __restrict__ w_list,
    float* __restrict__ ybuf)
{
  // grid = 8 xcd * 16 m * 16 g-hi = 2048; g = (e,ks,n) in 0..127
  int id = blockIdx.x;
  int xcd = id & 7;
  int rest = id >> 3;
  int mslot = rest & 15;
  int g = (rest >> 4) * 8 + xcd;
  int e = g >> 4;
  int ks = (g >> 3) & 1;
  int n0 = (g & 7) * 128;
  int cnt = counts[e];
  int m0 = mslot * 128;
  if (m0 >= cnt) return;

  __shared__ short As[128 * 32];
  __shared__ short Bs[128 * 32];

  int tid = threadIdx.x;
  int hb = base[e];
  int kbeg = ks * KSPLIT_LEN, kend = kbeg + KSPLIT_LEN;

  int sr = tid >> 1;
  int h = tid & 1;
  int key = (sr >> 1) & 3;
  int pair = ((2 * h) ^ key) >> 1;
  int sw = (key & 1) * 8;
  int ra = m0 + sr; if (ra >= cnt) ra = cnt - 1;
  const short* gA = hbuf + (size_t)(hb + ra) * INTER + pair * 16;
  size_t ebase = (size_t)e * (HIDDEN * INTER);
  const short* gBb = wdT + ebase + (size_t)(2 * pair) * (HIDDEN * 8)
                         + (size_t)(n0 + sr) * 8;
  short* wA0 = &As[sr * 32 + h * 16 + sw];
  short* wA1 = &As[sr * 32 + h * 16 + (8 - sw)];
  short* wB0 = &Bs[sr * 32 + h * 16 + sw];
  short* wB1 = &Bs[sr * 32 + h * 16 + (8 - sw)];

  int wv = tid >> 6, lane = tid & 63;
  int wm = wv & 1, wn = wv >> 1;
  int q = lane >> 4, ml = lane & 15;
  int chk = q ^ ((ml >> 1) & 3);
  const short* ard = &As[(wm * 64 + ml) * 32 + chk * 8];
  const short* brd = &Bs[(wn * 64 + ml) * 32 + chk * 8];

  f32x4 acc[4][4];
#pragma unroll
  for (int i = 0; i < 4; ++i)
#pragma unroll
    for (int j = 0; j < 4; ++j) acc[i][j] = (f32x4)0.f;

  size_t kboff0 = (size_t)(kbeg >> 5) * (4 * HIDDEN * 8);
  s16x8 a0 = *(const s16x8*)(gA + kbeg);  s16x8 a1 = *(const s16x8*)(gA + kbeg + 8);
  s16x8 b0 = *(const s16x8*)(gBb + kboff0);
  s16x8 b1 = *(const s16x8*)(gBb + kboff0 + HIDDEN * 8);

  for (int k0 = kbeg; k0 < kend; k0 += 32) {
    __syncthreads();
    *(s16x8*)wA0 = a0; *(s16x8*)wA1 = a1;
    *(s16x8*)wB0 = b0; *(s16x8*)wB1 = b1;
    __syncthreads();

    int kn = k0 + 32; if (kn >= kend) kn = kbeg;
    size_t kboff = (size_t)(kn >> 5) * (4 * HIDDEN * 8);
    a0 = *(const s16x8*)(gA + kn);  a1 = *(const s16x8*)(gA + kn + 8);
    b0 = *(const s16x8*)(gBb + kboff);
    b1 = *(const s16x8*)(gBb + kboff + HIDDEN * 8);

    s16x8 af[4], bf[4];
#pragma unroll
    for (int i = 0; i < 4; ++i) af[i] = *(const s16x8*)(ard + i * 16 * 32);
#pragma unroll
    for (int j = 0; j < 4; ++j) bf[j] = *(const s16x8*)(brd + j * 16 * 32);
#pragma unroll
    for (int i = 0; i < 4; ++i)
#pragma unroll
      for (int j = 0; j < 4; ++j)
        acc[i][j] = __builtin_amdgcn_mfma_f32_16x16x32_bf16(af[i], bf[j], acc[i][j], 0, 0, 0);
  }

#pragma unroll
  for (int i = 0; i < 4; ++i)
#pragma unroll
    for (int ii = 0; ii < 4; ++ii) {
      int r = m0 + wm * 64 + i * 16 + q * 4 + ii;
      if (r < cnt) {
        int ent = tok_list[e * NTOK + r];
        int tok = ent & 0xFFFF, slot = ent >> 16;
        float wgt = w_list[e * NTOK + r];
        float* yp = ybuf + ((size_t)(slot * 2 + ks) * NTOK + tok) * HIDDEN
                    + n0 + wn * 64 + ml;
#pragma unroll
        for (int j = 0; j < 4; ++j)
          yp[j * 16] = acc[i][j][ii] * wgt;
      }
    }
}

// ---------------------------------------------------------------------------
// out = sum of 4 ybuf slabs (every element written -> no out memset needed)
// ---------------------------------------------------------------------------
__global__ __launch_bounds__(256) void combine_kernel(
    const float* __restrict__ ybuf, float* __restrict__ out)
{
  size_t i = (size_t)blockIdx.x * 256 + threadIdx.x;
  const size_t S = (size_t)NTOK * HIDDEN / 4;
  float4 a = ((const float4*)ybuf)[i];
  float4 b = ((const float4*)ybuf)[i + S];
  float4 c = ((const float4*)ybuf)[i + 2 * S];
  float4 d = ((const float4*)ybuf)[i + 3 * S];
  float4 o;
  o.x = (a.x + b.x) + (c.x + d.x);
  o.y = (a.y + b.y) + (c.y + d.y);
  o.z = (a.z + b.z) + (c.z + d.z);
  o.w = (a.w + b.w) + (c.w + d.w);
  ((float4*)out)[i] = o;
}

// ---------------------------------------------------------------------------
// ws layout (bytes):
//   0..32           counts[8]
//   32..64          base[8]
//   64..65600       tok_list[8][2048]  (token | slot<<16)
//   65600..131136   w_list[8][2048]
//   131136..139328  ce[2048]
//   139328..155712  cw[2048] float2
//   155712          xb   bf16 [2048][1024]      (4 MB)
//   +4 MB           wgT  bf16 slabs             (23.07 MB) } ybuf[4] (32 MB
//   +23.07 MB       wuT  bf16 slabs             (23.07 MB) } fp32) aliases
//                                                          } wgT+wuT after
//                                                          } gateup completes
//   +23.07 MB       wdT  bf16 slabs
//   +23.07 MB       hbuf bf16 [4096][1408]      (11.5 MB)
//   total ~85.2 MB
// ---------------------------------------------------------------------------
extern "C" void kernel_launch(void* const* d_in, const int* in_sizes, int n_in,
                              void* d_out, int out_size, void* d_ws, size_t ws_size,
                              hipStream_t stream)
{
  const float* x  = (const float*)d_in[0];
  const float* rw = (const float*)d_in[1];
  const float* wg = (const float*)d_in[2];
  const float* wu = (const float*)d_in[3];
  const float* wd = (const float*)d_in[4];
  float* out = (float*)d_out;

  char* ws = (char*)d_ws;
  int*    counts   = (int*)(ws);
  int*    base     = (int*)(ws + 32);
  int*    tok_list = (int*)(ws + 64);
  float*  w_list   = (float*)(ws + 64 + NEXP * NTOK * 4);
  size_t off = 64 + 2 * (size_t)NEXP * NTOK * 4;
  int*    ce = (int*)(ws + off);     off += NTOK * 4;
  float2* cw = (float2*)(ws + off);  off += NTOK * 8;
  short* xb  = (short*)(ws + off);  off += (size_t)NTOK * HIDDEN * 2;
  short* wgT = (short*)(ws + off);  off += (size_t)NEXP * HIDDEN * INTER * 2;
  short* wuT = (short*)(ws + off);  off += (size_t)NEXP * HIDDEN * INTER * 2;
  short* wdT = (short*)(ws + off);  off += (size_t)NEXP * HIDDEN * INTER * 2;
  short* hbuf = (short*)(ws + off);
  float* ybuf = (float*)wgT;   // wgT+wuT dead after gateup; 32 MB fits in 46 MB

  router_choice<<<NTOK / 4, 256, 0, stream>>>(x, rw, ce, cw, xb);
  build_lists<<<NEXP, 256, 0, stream>>>(ce, cw, counts, base, tok_list, w_list);

  wconv<<<4224, 256, 0, stream>>>(wg, wu, wd, wgT, wuT, wdT);

  gateup_mfma<<<8 * 16 * 11, 256, 0, stream>>>(xb, wgT, wuT, counts, base, tok_list, hbuf);
  down_mfma<<<8 * 16 * 16, 256, 0, stream>>>(hbuf, wdT, counts, base, tok_list, w_list, ybuf);

  combine_kernel<<<(NTOK * HIDDEN / 4) / 256, 256, 0, stream>>>(ybuf, out);
}

// Round 3
// 265.984 us; speedup vs baseline: 1.0804x; 1.0143x over previous
//
#include <hip/hip_runtime.h>
#include <math.h>

#define HIDDEN 1024
#define INTER  1408
#define NEXP   8
#define NTOK   2048
#define KSPLIT_LEN 704   // INTER/2

typedef short s16x8 __attribute__((ext_vector_type(8)));   // 8 bf16 MFMA operand
typedef float f32x4 __attribute__((ext_vector_type(4)));   // MFMA accumulator

static __device__ __forceinline__ short f2b(float f) {
  union { float f; unsigned u; } v; v.f = f;
  unsigned u = v.u;
  unsigned r = (u + 0x7FFFu + ((u >> 16) & 1u)) >> 16;   // RNE
  return (short)r;
}

// ---------------------------------------------------------------------------
// Transposed-weight layout (chunk-slab form), chosen so the TRANSPOSE writes
// are perfectly sequential:
//   wT[e][kb][kc][n][8]  (bf16), kb = k/32, kc = (k%32)/8, n = output column.
// GEMM staging reads chunk c of row n at elem offset ((kb*4+c)*N + n)*8.
// ---------------------------------------------------------------------------

// ---------------------------------------------------------------------------
// Router phase 1: one wave per token, fp32 exact, NO atomics.
// Writes per-token choice: ce[t] = e0 | e1<<8, cw[t] = (w0, w1).
// FUSED: also emits xb (bf16 copy of x).
// ---------------------------------------------------------------------------
__global__ __launch_bounds__(256) void router_choice(
    const float* __restrict__ x, const float* __restrict__ rw,
    int* __restrict__ ce, float2* __restrict__ cw, short* __restrict__ xb)
{
  int wave = threadIdx.x >> 6;
  int lane = threadIdx.x & 63;
  int t = blockIdx.x * 4 + wave;
  if (t >= NTOK) return;
  const float* xt = x + (size_t)t * HIDDEN;
  float xr[16];
#pragma unroll
  for (int i = 0; i < 16; ++i) xr[i] = xt[lane + 64 * i];

  short* xo = xb + (size_t)t * HIDDEN;
#pragma unroll
  for (int i = 0; i < 16; ++i) xo[lane + 64 * i] = f2b(xr[i]);

  float logits[NEXP];
#pragma unroll
  for (int e = 0; e < NEXP; ++e) {
    const float* w = rw + e * HIDDEN;
    float acc = 0.f;
#pragma unroll
    for (int i = 0; i < 16; ++i) acc = fmaf(xr[i], w[lane + 64 * i], acc);
#pragma unroll
    for (int off = 32; off > 0; off >>= 1) acc += __shfl_xor(acc, off);
    logits[e] = acc;
  }
  if (lane == 0) {
    float mx = logits[0];
#pragma unroll
    for (int e = 1; e < NEXP; ++e) mx = fmaxf(mx, logits[e]);
    float p[NEXP];
#pragma unroll
    for (int e = 0; e < NEXP; ++e) p[e] = expf(logits[e] - mx);
    int i0 = 0;
#pragma unroll
    for (int e = 1; e < NEXP; ++e) if (p[e] > p[i0]) i0 = e;
    int i1 = (i0 == 0) ? 1 : 0;
#pragma unroll
    for (int e = 0; e < NEXP; ++e) { if (e != i0 && p[e] > p[i1]) i1 = e; }
    float denom = p[i0] + p[i1];
    ce[t] = i0 | (i1 << 8);
    cw[t] = make_float2(p[i0] / denom, p[i1] / denom);
  }
}

// ---------------------------------------------------------------------------
// Router phase 2: one block per expert. Deterministic compaction (stable in
// token order) via register histogram + LDS scan.
// ---------------------------------------------------------------------------
__global__ __launch_bounds__(256) void build_lists(
    const int* __restrict__ ce, const float2* __restrict__ cw,
    int* __restrict__ counts, int* __restrict__ base,
    int* __restrict__ tok_list, float* __restrict__ w_list)
{
  int e = blockIdx.x;          // 0..7
  int tid = threadIdx.x;       // each thread owns tokens [8*tid, 8*tid+8)
  __shared__ int hall[256][8];
  __shared__ int hsum[8];
  __shared__ int scan[256];

  int cloc[8];                 // cached choices
  int h[8] = {0,0,0,0,0,0,0,0};
  int myc = 0;
#pragma unroll
  for (int j = 0; j < 8; ++j) {
    int c = ce[tid * 8 + j];
    cloc[j] = c;
    int e0 = c & 255, e1 = (c >> 8) & 255;
    h[e0]++; h[e1]++;
    myc += (e0 == e) + (e1 == e);
  }
#pragma unroll
  for (int k = 0; k < 8; ++k) hall[tid][k] = h[k];
  scan[tid] = myc;
  __syncthreads();

  if (tid < 8) {
    int s = 0;
    for (int i = 0; i < 256; ++i) s += hall[i][tid];
    hsum[tid] = s;
  }
  // Hillis-Steele inclusive scan over per-thread counts
  int v = myc;
  for (int off = 1; off < 256; off <<= 1) {
    int prev = (tid >= off) ? scan[tid - off] : 0;
    __syncthreads();
    v = v + prev;
    scan[tid] = v;
    __syncthreads();
  }
  int pos = v - myc;           // exclusive prefix = my first slot

  if (tid == 0) {
    int b = 0;
    for (int k = 0; k < e; ++k) b += hsum[k];
    base[e] = b;
    counts[e] = hsum[e];
  }

#pragma unroll
  for (int j = 0; j < 8; ++j) {
    int t = tid * 8 + j;
    int c = cloc[j];
    int e0 = c & 255, e1 = (c >> 8) & 255;
    if (e0 == e) {
      float2 w = cw[t];
      tok_list[e * NTOK + pos] = t;                // slot 0
      w_list[e * NTOK + pos] = w.x;
      pos++;
    } else if (e1 == e) {
      float2 w = cw[t];
      tok_list[e * NTOK + pos] = t | (1 << 16);    // slot 1
      w_list[e * NTOK + pos] = w.y;
      pos++;
    }
  }
}

// ---------------------------------------------------------------------------
// Weight transpose-convert into chunk-slab layout, v3.
// r2 A/B isolated the READS as the limiter (dword 4B/lane stream caps at
// ~2.3 TB/s; copy ceiling needs 16B/lane). v3 reads float4 and keeps r2's
// sequential 1KB/instr stores.
// Per wave (32k x 64n tile of one matrix):
//   - 8 x global_load_dwordx4: lane (g=l>>4, i=l&15), load j covers row
//     kb*32 + 8g + j, cols nt*64 + 4i..4i+3   (1KB coalesced per instr)
//   - lane now owns 4 complete output chunks IN REGISTER:
//     chunk (kc=g, col 4i+c) = 8 consecutive k, pack fp32->bf16 (16B)
//   - redistribute via private 4KB LDS slice (no block barrier, intra-wave):
//     write slot g*64 + ((4i+c)^g), read slot kc*64 + (lane^kc)
//     (XOR keeps per-instr bank load uniform: 8 accesses/bank = minimum)
//   - 4 x global_store_dwordx4: slab kc, cols nt*64 + lane -> 64 consecutive
//     16B chunks = 1KB fully-covered sequential per instr (same as r2)
// VMEM instrs 36 -> 12; read granularity 4B -> 16B per lane.
// 704 waves per (mat, e); 16896 waves total = 4224 blocks.
// ---------------------------------------------------------------------------
__global__ __launch_bounds__(256) void wconv(
    const float* __restrict__ wg, const float* __restrict__ wu,
    const float* __restrict__ wd,
    short* __restrict__ wgT, short* __restrict__ wuT, short* __restrict__ wdT)
{
  __shared__ short lds[4][2048];    // 4KB per wave, private slices
  int wid = threadIdx.x >> 6;
  int lane = threadIdx.x & 63;
  int gw = blockIdx.x * 4 + wid;    // global wave id 0..16895
  int mat = gw / 5632;              // 5632 = 8 experts * 704 waves
  int r = gw - mat * 5632;
  int e = r / 704;
  int t = r - e * 704;

  const float* src; short* dst; int N, nstr;
  if (mat == 0)      { src = wg; dst = wgT; N = INTER;  nstr = 22; }
  else if (mat == 1) { src = wu; dst = wuT; N = INTER;  nstr = 22; }
  else               { src = wd; dst = wdT; N = HIDDEN; nstr = 16; }

  int kb = t / nstr, nt = t - kb * nstr;
  int g = lane >> 4, i = lane & 15;

  const float* se = src + (size_t)e * (HIDDEN * INTER)
                        + (size_t)(kb * 32 + 8 * g) * N + nt * 64 + 4 * i;

  float vf[32];                     // vf[4*j + c] = row (8g+j), col (4i+c)
#pragma unroll
  for (int j = 0; j < 8; ++j)
    *(float4*)&vf[4 * j] = *(const float4*)(se + (size_t)j * N);

  short* lw = lds[wid];
  // pack chunk c (col 4i+c, k = kb*32+8g .. +7) and stage to swizzled slot
#pragma unroll
  for (int c = 0; c < 4; ++c) {
    unsigned pk[4];
#pragma unroll
    for (int m = 0; m < 4; ++m) {
      unsigned lo = (unsigned short)f2b(vf[8 * m + c]);       // j = 2m
      unsigned hi = (unsigned short)f2b(vf[8 * m + 4 + c]);   // j = 2m+1
      pk[m] = lo | (hi << 16);
    }
    int slot = g * 64 + ((4 * i + c) ^ g);
    *(uint4*)(lw + slot * 8) = make_uint4(pk[0], pk[1], pk[2], pk[3]);
  }

  // intra-wave redistribute: lane picks up (slab kc, col lane)
  uint4 outv[4];
#pragma unroll
  for (int kc = 0; kc < 4; ++kc)
    outv[kc] = *(const uint4*)(lw + (kc * 64 + (lane ^ kc)) * 8);

  short* de = dst + (size_t)e * (HIDDEN * INTER);
#pragma unroll
  for (int kc = 0; kc < 4; ++kc)
    *(uint4*)(de + ((size_t)(kb * 4 + kc) * N + nt * 64 + lane) * 8) = outv[kc];
}

// ---------------------------------------------------------------------------
// Staging geometry (both GEMMs), XOR-swizzled LDS [row][4 chunks]:
//   phys chunk p of row r holds logical chunk p ^ ((r>>1)&3); fragment read
//   (lane ml, quad q) uses phys q ^ ((ml>>1)&3) -> 2-way aliasing only (free).
//   Measured 0 LDS bank conflicts. Global B-source is the chunk-slab
//   layout: logical chunk c of row n at ((kb*4+c)*N + n)*8 elems.
// ---------------------------------------------------------------------------

// ---------------------------------------------------------------------------
// Phase A: H = silu(X@Wg)*(X@Wu). Tile M=128 N=128 BK=32, 4 waves (2x2),
// 4x4 MFMAs each for gate AND up; register prefetch issued after the
// LDS-ready barrier. XCD-swizzled flat grid for weight-strip L2 locality.
// ---------------------------------------------------------------------------
__global__ __launch_bounds__(256, 2) void gateup_mfma(
    const short* __restrict__ xb, const short* __restrict__ wgT,
    const short* __restrict__ wuT,
    const int* __restrict__ counts, const int* __restrict__ base,
    const int* __restrict__ tok_list, short* __restrict__ hbuf)
{
  // grid = 8 xcd * 16 m * 11 g-hi = 1408; g = (e,n) in 0..87
  int id = blockIdx.x;
  int xcd = id & 7;
  int rest = id >> 3;
  int mslot = rest & 15;
  int g = (rest >> 4) * 8 + xcd;
  int e = g / 11;
  int n0 = (g - e * 11) * 128;
  int cnt = counts[e];
  int m0 = mslot * 128;
  if (m0 >= cnt) return;

  __shared__ short As[128 * 32];
  __shared__ short Bg[128 * 32];
  __shared__ short Bu[128 * 32];
  __shared__ int toks[128];

  int tid = threadIdx.x;
  if (tid < 128) {
    int r = m0 + tid;
    toks[tid] = tok_list[e * NTOK + (r < cnt ? r : cnt - 1)] & 0xFFFF;
  }
  __syncthreads();

  int sr = tid >> 1;             // 0..127
  int h = tid & 1;
  int key = (sr >> 1) & 3;
  int pair = ((2 * h) ^ key) >> 1;           // which 32B global block
  int sw = (key & 1) * 8;                    // swap c0/c1 on write
  const short* gA = xb + (size_t)toks[sr] * HIDDEN + pair * 16;
  // chunk-slab B base: logical chunk c0 = 2*pair of row n0+sr
  size_t ebase = (size_t)e * (HIDDEN * INTER);
  size_t boff = (size_t)(2 * pair) * (INTER * 8) + (size_t)(n0 + sr) * 8;
  const short* gGb = wgT + ebase + boff;
  const short* gUb = wuT + ebase + boff;
  short* wA0 = &As[sr * 32 + h * 16 + sw];
  short* wA1 = &As[sr * 32 + h * 16 + (8 - sw)];
  short* wG0 = &Bg[sr * 32 + h * 16 + sw];
  short* wG1 = &Bg[sr * 32 + h * 16 + (8 - sw)];
  short* wU0 = &Bu[sr * 32 + h * 16 + sw];
  short* wU1 = &Bu[sr * 32 + h * 16 + (8 - sw)];

  int wv = tid >> 6, lane = tid & 63;
  int wm = wv & 1, wn = wv >> 1;
  int q = lane >> 4, ml = lane & 15;
  int chk = q ^ ((ml >> 1) & 3);
  const short* ard = &As[(wm * 64 + ml) * 32 + chk * 8];
  const short* grd = &Bg[(wn * 64 + ml) * 32 + chk * 8];
  const short* urd = &Bu[(wn * 64 + ml) * 32 + chk * 8];

  f32x4 accg[4][4], accu[4][4];
#pragma unroll
  for (int i = 0; i < 4; ++i)
#pragma unroll
    for (int j = 0; j < 4; ++j) { accg[i][j] = (f32x4)0.f; accu[i][j] = (f32x4)0.f; }

  s16x8 a0 = *(const s16x8*)(gA);     s16x8 a1 = *(const s16x8*)(gA + 8);
  s16x8 g0 = *(const s16x8*)(gGb);    s16x8 g1 = *(const s16x8*)(gGb + INTER * 8);
  s16x8 u0 = *(const s16x8*)(gUb);    s16x8 u1 = *(const s16x8*)(gUb + INTER * 8);

  for (int k0 = 0; k0 < HIDDEN; k0 += 32) {
    __syncthreads();
    *(s16x8*)wA0 = a0; *(s16x8*)wA1 = a1;
    *(s16x8*)wG0 = g0; *(s16x8*)wG1 = g1;
    *(s16x8*)wU0 = u0; *(s16x8*)wU1 = u1;
    __syncthreads();

    int kn = (k0 + 32) & (HIDDEN - 1);
    size_t kboff = (size_t)(kn >> 5) * (4 * INTER * 8);
    a0 = *(const s16x8*)(gA + kn);         a1 = *(const s16x8*)(gA + kn + 8);
    g0 = *(const s16x8*)(gGb + kboff);     g1 = *(const s16x8*)(gGb + kboff + INTER * 8);
    u0 = *(const s16x8*)(gUb + kboff);     u1 = *(const s16x8*)(gUb + kboff + INTER * 8);

    s16x8 af[4], gf[4], uf[4];
#pragma unroll
    for (int i = 0; i < 4; ++i) af[i] = *(const s16x8*)(ard + i * 16 * 32);
#pragma unroll
    for (int j = 0; j < 4; ++j) {
      gf[j] = *(const s16x8*)(grd + j * 16 * 32);
      uf[j] = *(const s16x8*)(urd + j * 16 * 32);
    }
#pragma unroll
    for (int i = 0; i < 4; ++i)
#pragma unroll
      for (int j = 0; j < 4; ++j) {
        accg[i][j] = __builtin_amdgcn_mfma_f32_16x16x32_bf16(af[i], gf[j], accg[i][j], 0, 0, 0);
        accu[i][j] = __builtin_amdgcn_mfma_f32_16x16x32_bf16(af[i], uf[j], accu[i][j], 0, 0, 0);
      }
  }

  int hb = base[e];
#pragma unroll
  for (int i = 0; i < 4; ++i)
#pragma unroll
    for (int ii = 0; ii < 4; ++ii) {
      int r = m0 + wm * 64 + i * 16 + q * 4 + ii;
      if (r < cnt) {
        short* hp = hbuf + (size_t)(hb + r) * INTER + n0 + wn * 64 + ml;
#pragma unroll
        for (int j = 0; j < 4; ++j) {
          float gg = accg[i][j][ii], uu = accu[i][j][ii];
          float hh = (gg / (1.f + __expf(-gg))) * uu;
          hp[j * 16] = f2b(hh);
        }
      }
    }
}

// ---------------------------------------------------------------------------
// Phase B: Y = H @ Wd, K-split x2; scaled partials to ybuf[slot*2+ks][token]
// with plain stores (no atomics).
// ---------------------------------------------------------------------------
__global__ __launch_bounds__(256, 3) void down_mfma(
    const short* __restrict__ hbuf, const short* __restrict__ wdT,
    const int* __restrict__ counts, const int* __restrict__ base,
    const int* __restrict__ tok_list, const float* __restrict__ w_list,
    float* __restrict__ ybuf)
{
  // grid = 8 xcd * 16 m * 16 g-hi = 2048; g = (e,ks,n) in 0..127
  int id = blockIdx.x;
  int xcd = id & 7;
  int rest = id >> 3;
  int mslot = rest & 15;
  int g = (rest >> 4) * 8 + xcd;
  int e = g >> 4;
  int ks = (g >> 3) & 1;
  int n0 = (g & 7) * 128;
  int cnt = counts[e];
  int m0 = mslot * 128;
  if (m0 >= cnt) return;

  __shared__ short As[128 * 32];
  __shared__ short Bs[128 * 32];

  int tid = threadIdx.x;
  int hb = base[e];
  int kbeg = ks * KSPLIT_LEN, kend = kbeg + KSPLIT_LEN;

  int sr = tid >> 1;
  int h = tid & 1;
  int key = (sr >> 1) & 3;
  int pair = ((2 * h) ^ key) >> 1;
  int sw = (key & 1) * 8;
  int ra = m0 + sr; if (ra >= cnt) ra = cnt - 1;
  const short* gA = hbuf + (size_t)(hb + ra) * INTER + pair * 16;
  size_t ebase = (size_t)e * (HIDDEN * INTER);
  const short* gBb = wdT + ebase + (size_t)(2 * pair) * (HIDDEN * 8)
                         + (size_t)(n0 + sr) * 8;
  short* wA0 = &As[sr * 32 + h * 16 + sw];
  short* wA1 = &As[sr * 32 + h * 16 + (8 - sw)];
  short* wB0 = &Bs[sr * 32 + h * 16 + sw];
  short* wB1 = &Bs[sr * 32 + h * 16 + (8 - sw)];

  int wv = tid >> 6, lane = tid & 63;
  int wm = wv & 1, wn = wv >> 1;
  int q = lane >> 4, ml = lane & 15;
  int chk = q ^ ((ml >> 1) & 3);
  const short* ard = &As[(wm * 64 + ml) * 32 + chk * 8];
  const short* brd = &Bs[(wn * 64 + ml) * 32 + chk * 8];

  f32x4 acc[4][4];
#pragma unroll
  for (int i = 0; i < 4; ++i)
#pragma unroll
    for (int j = 0; j < 4; ++j) acc[i][j] = (f32x4)0.f;

  size_t kboff0 = (size_t)(kbeg >> 5) * (4 * HIDDEN * 8);
  s16x8 a0 = *(const s16x8*)(gA + kbeg);  s16x8 a1 = *(const s16x8*)(gA + kbeg + 8);
  s16x8 b0 = *(const s16x8*)(gBb + kboff0);
  s16x8 b1 = *(const s16x8*)(gBb + kboff0 + HIDDEN * 8);

  for (int k0 = kbeg; k0 < kend; k0 += 32) {
    __syncthreads();
    *(s16x8*)wA0 = a0; *(s16x8*)wA1 = a1;
    *(s16x8*)wB0 = b0; *(s16x8*)wB1 = b1;
    __syncthreads();

    int kn = k0 + 32; if (kn >= kend) kn = kbeg;
    size_t kboff = (size_t)(kn >> 5) * (4 * HIDDEN * 8);
    a0 = *(const s16x8*)(gA + kn);  a1 = *(const s16x8*)(gA + kn + 8);
    b0 = *(const s16x8*)(gBb + kboff);
    b1 = *(const s16x8*)(gBb + kboff + HIDDEN * 8);

    s16x8 af[4], bf[4];
#pragma unroll
    for (int i = 0; i < 4; ++i) af[i] = *(const s16x8*)(ard + i * 16 * 32);
#pragma unroll
    for (int j = 0; j < 4; ++j) bf[j] = *(const s16x8*)(brd + j * 16 * 32);
#pragma unroll
    for (int i = 0; i < 4; ++i)
#pragma unroll
      for (int j = 0; j < 4; ++j)
        acc[i][j] = __builtin_amdgcn_mfma_f32_16x16x32_bf16(af[i], bf[j], acc[i][j], 0, 0, 0);
  }

#pragma unroll
  for (int i = 0; i < 4; ++i)
#pragma unroll
    for (int ii = 0; ii < 4; ++ii) {
      int r = m0 + wm * 64 + i * 16 + q * 4 + ii;
      if (r < cnt) {
        int ent = tok_list[e * NTOK + r];
        int tok = ent & 0xFFFF, slot = ent >> 16;
        float wgt = w_list[e * NTOK + r];
        float* yp = ybuf + ((size_t)(slot * 2 + ks) * NTOK + tok) * HIDDEN
                    + n0 + wn * 64 + ml;
#pragma unroll
        for (int j = 0; j < 4; ++j)
          yp[j * 16] = acc[i][j][ii] * wgt;
      }
    }
}

// ---------------------------------------------------------------------------
// out = sum of 4 ybuf slabs (every element written -> no out memset needed)
// ---------------------------------------------------------------------------
__global__ __launch_bounds__(256) void combine_kernel(
    const float* __restrict__ ybuf, float* __restrict__ out)
{
  size_t i = (size_t)blockIdx.x * 256 + threadIdx.x;
  const size_t S = (size_t)NTOK * HIDDEN / 4;
  float4 a = ((const float4*)ybuf)[i];
  float4 b = ((const float4*)ybuf)[i + S];
  float4 c = ((const float4*)ybuf)[i + 2 * S];
  float4 d = ((const float4*)ybuf)[i + 3 * S];
  float4 o;
  o.x = (a.x + b.x) + (c.x + d.x);
  o.y = (a.y + b.y) + (c.y + d.y);
  o.z = (a.z + b.z) + (c.z + d.z);
  o.w = (a.w + b.w) + (c.w + d.w);
  ((float4*)out)[i] = o;
}

// ---------------------------------------------------------------------------
// ws layout (bytes):
//   0..32           counts[8]
//   32..64          base[8]
//   64..65600       tok_list[8][2048]  (token | slot<<16)
//   65600..131136   w_list[8][2048]
//   131136..139328  ce[2048]
//   139328..155712  cw[2048] float2
//   155712          xb   bf16 [2048][1024]      (4 MB)
//   +4 MB           wgT  bf16 slabs             (23.07 MB) } ybuf[4] (32 MB
//   +23.07 MB       wuT  bf16 slabs             (23.07 MB) } fp32) aliases
//                                                          } wgT+wuT after
//                                                          } gateup completes
//   +23.07 MB       wdT  bf16 slabs
//   +23.07 MB       hbuf bf16 [4096][1408]      (11.5 MB)
//   total ~85.2 MB
// ---------------------------------------------------------------------------
extern "C" void kernel_launch(void* const* d_in, const int* in_sizes, int n_in,
                              void* d_out, int out_size, void* d_ws, size_t ws_size,
                              hipStream_t stream)
{
  const float* x  = (const float*)d_in[0];
  const float* rw = (const float*)d_in[1];
  const float* wg = (const float*)d_in[2];
  const float* wu = (const float*)d_in[3];
  const float* wd = (const float*)d_in[4];
  float* out = (float*)d_out;

  char* ws = (char*)d_ws;
  int*    counts   = (int*)(ws);
  int*    base     = (int*)(ws + 32);
  int*    tok_list = (int*)(ws + 64);
  float*  w_list   = (float*)(ws + 64 + NEXP * NTOK * 4);
  size_t off = 64 + 2 * (size_t)NEXP * NTOK * 4;
  int*    ce = (int*)(ws + off);     off += NTOK * 4;
  float2* cw = (float2*)(ws + off);  off += NTOK * 8;
  short* xb  = (short*)(ws + off);  off += (size_t)NTOK * HIDDEN * 2;
  short* wgT = (short*)(ws + off);  off += (size_t)NEXP * HIDDEN * INTER * 2;
  short* wuT = (short*)(ws + off);  off += (size_t)NEXP * HIDDEN * INTER * 2;
  short* wdT = (short*)(ws + off);  off += (size_t)NEXP * HIDDEN * INTER * 2;
  short* hbuf = (short*)(ws + off);
  float* ybuf = (float*)wgT;   // wgT+wuT dead after gateup; 32 MB fits in 46 MB

  router_choice<<<NTOK / 4, 256, 0, stream>>>(x, rw, ce, cw, xb);
  build_lists<<<NEXP, 256, 0, stream>>>(ce, cw, counts, base, tok_list, w_list);

  wconv<<<4224, 256, 0, stream>>>(wg, wu, wd, wgT, wuT, wdT);

  gateup_mfma<<<8 * 16 * 11, 256, 0, stream>>>(xb, wgT, wuT, counts, base, tok_list, hbuf);
  down_mfma<<<8 * 16 * 16, 256, 0, stream>>>(hbuf, wdT, counts, base, tok_list, w_list, ybuf);

  combine_kernel<<<(NTOK * HIDDEN / 4) / 256, 256, 0, stream>>>(ybuf, out);
}

// Round 4
// 255.131 us; speedup vs baseline: 1.1264x; 1.0425x over previous
//
#include <hip/hip_runtime.h>
#include <math.h>

#define HIDDEN 1024
#define INTER  1408
#define NEXP   8
#define NTOK   2048
#define KSPLIT_LEN 704   // INTER/2

typedef short s16x8 __attribute__((ext_vector_type(8)));   // 8 bf16 MFMA operand
typedef float f32x4 __attribute__((ext_vector_type(4)));   // MFMA accumulator

static __device__ __forceinline__ short f2b(float f) {
  union { float f; unsigned u; } v; v.f = f;
  unsigned u = v.u;
  unsigned r = (u + 0x7FFFu + ((u >> 16) & 1u)) >> 16;   // RNE
  return (short)r;
}

// ---------------------------------------------------------------------------
// Transposed-weight layout (chunk-slab form):
//   wT[e][slab][n][8]  (bf16), slab = k/8, n = output column.
// GEMM staging reads logical chunk c of row n at ((kb*4+c)*N + n)*8 elems.
//
// wconv v4: every READ instruction is one fully-contiguous row segment.
//   Full task (8 k-rows x 256 cols): 8 loads of 1KB (64 lanes x float4 in ONE
//   row). Lane l accumulates rows r0..r0+7 x cols 4l..4l+3 -> owns 4 complete
//   16B output chunks. Intra-wave LDS shuffle (XOR bank swizzle, no barrier),
//   then 4 stores of 1KB fully-contiguous (64 consecutive chunks of slab r0/8).
//   Rem task (N=1408 tail, 16 rows x 128 cols): 8 loads of 2x512B segments
//   (rows j and j+8 at same col window); lanes<32 own slab kcu2, lanes>=32
//   own slab kcu2+1; same shuffle+stores.
// v2/v3 A/B showed 256B read segments cap at ~2.4 TB/s regardless of per-lane
// width; writes at 1KB/instr run full speed -> segment size is the lever.
// ---------------------------------------------------------------------------
static __device__ __forceinline__ void wconv_full(
    const float* __restrict__ se, short* __restrict__ de, int N,
    int kcu, int col0, int lane, short* lw)
{
  const float* p = se + (size_t)kcu * 8 * N + col0 + 4 * lane;
  float vf[32];                       // vf[4j+c] = row j, col 4l+c
#pragma unroll
  for (int j = 0; j < 8; ++j)
    *(float4*)&vf[4 * j] = *(const float4*)(p + (size_t)j * N);

#pragma unroll
  for (int c = 0; c < 4; ++c) {
    unsigned pk[4];
#pragma unroll
    for (int m = 0; m < 4; ++m) {
      unsigned lo = (unsigned short)f2b(vf[8 * m + c]);       // row 2m
      unsigned hi = (unsigned short)f2b(vf[8 * m + 4 + c]);   // row 2m+1
      pk[m] = lo | (hi << 16);
    }
    int slot = 4 * lane + c;
    int phys = slot ^ ((slot >> 6) & 3);          // uniform 8 lanes/bank-group
    *(uint4*)(lw + phys * 8) = make_uint4(pk[0], pk[1], pk[2], pk[3]);
  }
  uint4 outv[4];
#pragma unroll
  for (int s = 0; s < 4; ++s) {
    int slot = 64 * s + lane;
    int phys = slot ^ s;                          // (slot>>6)&3 == s
    outv[s] = *(const uint4*)(lw + phys * 8);
  }
#pragma unroll
  for (int s = 0; s < 4; ++s)
    *(uint4*)(de + ((size_t)kcu * N + col0 + 64 * s + lane) * 8) = outv[s];
}

static __device__ __forceinline__ void wconv_rem(
    const float* __restrict__ se, short* __restrict__ de, int N,
    int row16, int lane, short* lw)
{
  // rows row16*16 .. +15, cols N-128 .. N-1  (used for N=1408 tail)
  int col0 = N - 128;
  int kcu2 = row16 * 2;
  int li = lane & 31, h2 = lane >> 5;
  const float* p = se + (size_t)(row16 * 16 + 8 * h2) * N + col0 + 4 * li;
  float vf[32];
#pragma unroll
  for (int j = 0; j < 8; ++j)
    *(float4*)&vf[4 * j] = *(const float4*)(p + (size_t)j * N);

#pragma unroll
  for (int c = 0; c < 4; ++c) {
    unsigned pk[4];
#pragma unroll
    for (int m = 0; m < 4; ++m) {
      unsigned lo = (unsigned short)f2b(vf[8 * m + c]);
      unsigned hi = (unsigned short)f2b(vf[8 * m + 4 + c]);
      pk[m] = lo | (hi << 16);
    }
    int slot = h2 * 128 + 4 * li + c;
    int phys = slot ^ ((slot >> 6) & 3);
    *(uint4*)(lw + phys * 8) = make_uint4(pk[0], pk[1], pk[2], pk[3]);
  }
  uint4 outv[4];
#pragma unroll
  for (int s = 0; s < 4; ++s) {
    int slot = (s >> 1) * 128 + (s & 1) * 64 + lane;
    int phys = slot ^ s;
    outv[s] = *(const uint4*)(lw + phys * 8);
  }
#pragma unroll
  for (int s = 0; s < 4; ++s)
    *(uint4*)(de + ((size_t)(kcu2 + (s >> 1)) * N + col0 + (s & 1) * 64 + lane) * 8)
        = outv[s];
}

// ---------------------------------------------------------------------------
// Fused kernel 1: router (blocks [0,512)) + wconv of wg,wu (blocks [512,3328)).
// Independent work: router feeds build_lists; wconv_gu feeds gateup. Sharing
// one launch removes a gap and lets both streams share BW.
// ---------------------------------------------------------------------------
__global__ __launch_bounds__(256) void router_wconv_gu(
    const float* __restrict__ x, const float* __restrict__ rw,
    const float* __restrict__ wg, const float* __restrict__ wu,
    int* __restrict__ ce, float2* __restrict__ cw, short* __restrict__ xb,
    short* __restrict__ wgT, short* __restrict__ wuT)
{
  __shared__ short lds[4][2048];
  int id = blockIdx.x;
  int wave = threadIdx.x >> 6;
  int lane = threadIdx.x & 63;

  if (id >= 512) {
    // ---- wconv wg/wu: 11264 wave-tasks ----
    int gw = (id - 512) * 4 + wave;
    int mat = gw / 5632;              // 0: wg, 1: wu
    int r = gw - mat * 5632;
    int e = r / 704;
    int t = r - e * 704;
    const float* se = (mat == 0 ? wg : wu) + (size_t)e * (HIDDEN * INTER);
    short*       de = (mat == 0 ? wgT : wuT) + (size_t)e * (HIDDEN * INTER);
    short* lw = lds[wave];
    if (t < 640) wconv_full(se, de, INTER, t / 5, (t % 5) * 256, lane, lw);
    else         wconv_rem (se, de, INTER, t - 640, lane, lw);
    return;
  }

  // ---- router: one wave per token, fp32 exact ----
  int t = id * 4 + wave;
  const float* xt = x + (size_t)t * HIDDEN;
  float xr[16];
#pragma unroll
  for (int i = 0; i < 16; ++i) xr[i] = xt[lane + 64 * i];

  short* xo = xb + (size_t)t * HIDDEN;
#pragma unroll
  for (int i = 0; i < 16; ++i) xo[lane + 64 * i] = f2b(xr[i]);

  float logits[NEXP];
#pragma unroll
  for (int e = 0; e < NEXP; ++e) {
    const float* w = rw + e * HIDDEN;
    float acc = 0.f;
#pragma unroll
    for (int i = 0; i < 16; ++i) acc = fmaf(xr[i], w[lane + 64 * i], acc);
#pragma unroll
    for (int off = 32; off > 0; off >>= 1) acc += __shfl_xor(acc, off);
    logits[e] = acc;
  }
  if (lane == 0) {
    float mx = logits[0];
#pragma unroll
    for (int e = 1; e < NEXP; ++e) mx = fmaxf(mx, logits[e]);
    float p[NEXP];
#pragma unroll
    for (int e = 0; e < NEXP; ++e) p[e] = expf(logits[e] - mx);
    int i0 = 0;
#pragma unroll
    for (int e = 1; e < NEXP; ++e) if (p[e] > p[i0]) i0 = e;
    int i1 = (i0 == 0) ? 1 : 0;
#pragma unroll
    for (int e = 0; e < NEXP; ++e) { if (e != i0 && p[e] > p[i1]) i1 = e; }
    float denom = p[i0] + p[i1];
    ce[t] = i0 | (i1 << 8);
    cw[t] = make_float2(p[i0] / denom, p[i1] / denom);
  }
}

// ---------------------------------------------------------------------------
// Router phase 2: one block per expert. Deterministic compaction (stable in
// token order) via register histogram + LDS scan.
// ---------------------------------------------------------------------------
__global__ __launch_bounds__(256) void build_lists(
    const int* __restrict__ ce, const float2* __restrict__ cw,
    int* __restrict__ counts, int* __restrict__ base,
    int* __restrict__ tok_list, float* __restrict__ w_list)
{
  int e = blockIdx.x;          // 0..7
  int tid = threadIdx.x;       // each thread owns tokens [8*tid, 8*tid+8)
  __shared__ int hall[256][8];
  __shared__ int hsum[8];
  __shared__ int scan[256];

  int cloc[8];                 // cached choices
  int h[8] = {0,0,0,0,0,0,0,0};
  int myc = 0;
#pragma unroll
  for (int j = 0; j < 8; ++j) {
    int c = ce[tid * 8 + j];
    cloc[j] = c;
    int e0 = c & 255, e1 = (c >> 8) & 255;
    h[e0]++; h[e1]++;
    myc += (e0 == e) + (e1 == e);
  }
#pragma unroll
  for (int k = 0; k < 8; ++k) hall[tid][k] = h[k];
  scan[tid] = myc;
  __syncthreads();

  if (tid < 8) {
    int s = 0;
    for (int i = 0; i < 256; ++i) s += hall[i][tid];
    hsum[tid] = s;
  }
  // Hillis-Steele inclusive scan over per-thread counts
  int v = myc;
  for (int off = 1; off < 256; off <<= 1) {
    int prev = (tid >= off) ? scan[tid - off] : 0;
    __syncthreads();
    v = v + prev;
    scan[tid] = v;
    __syncthreads();
  }
  int pos = v - myc;           // exclusive prefix = my first slot

  if (tid == 0) {
    int b = 0;
    for (int k = 0; k < e; ++k) b += hsum[k];
    base[e] = b;
    counts[e] = hsum[e];
  }

#pragma unroll
  for (int j = 0; j < 8; ++j) {
    int t = tid * 8 + j;
    int c = cloc[j];
    int e0 = c & 255, e1 = (c >> 8) & 255;
    if (e0 == e) {
      float2 w = cw[t];
      tok_list[e * NTOK + pos] = t;                // slot 0
      w_list[e * NTOK + pos] = w.x;
      pos++;
    } else if (e1 == e) {
      float2 w = cw[t];
      tok_list[e * NTOK + pos] = t | (1 << 16);    // slot 1
      w_list[e * NTOK + pos] = w.y;
      pos++;
    }
  }
}

// ---------------------------------------------------------------------------
// Fused kernel 2: wconv of wd (blocks [0,1408)) + gateup (blocks [1408,2816)).
// wdT is only needed by down_mfma, so its transpose overlaps gateup's MFMA
// time. wconv blocks dispatch first (short, pure-memory); 1408%8==0 keeps
// gateup's XCD-swizzle alignment.
// gateup: H = silu(X@Wg)*(X@Wu). Tile M=128 N=128 BK=32, 4 waves (2x2),
// 4x4 MFMAs each for gate AND up; register prefetch after the LDS barrier.
// ---------------------------------------------------------------------------
__global__ __launch_bounds__(256, 2) void gateup_wconv_d(
    const short* __restrict__ xb, const short* __restrict__ wgT,
    const short* __restrict__ wuT,
    const float* __restrict__ wd, short* __restrict__ wdT,
    const int* __restrict__ counts, const int* __restrict__ base,
    const int* __restrict__ tok_list, short* __restrict__ hbuf)
{
  __shared__ __align__(16) char smem[25088];   // 24KB tiles + 512B toks / 16KB wconv
  int id0 = blockIdx.x;
  int tid = threadIdx.x;

  if (id0 < 1408) {
    // ---- wconv wd: 5632 wave-tasks, N = HIDDEN ----
    int gw = id0 * 4 + (tid >> 6);
    int lane = tid & 63;
    int e = gw / 704;
    int t = gw - e * 704;
    const float* se = wd + (size_t)e * (HIDDEN * INTER);
    short*       de = wdT + (size_t)e * (HIDDEN * INTER);
    short* lw = (short*)smem + (tid >> 6) * 2048;
    wconv_full(se, de, HIDDEN, t >> 2, (t & 3) * 256, lane, lw);
    return;
  }

  // ---- gateup ----
  int id = id0 - 1408;         // 0..1407
  int xcd = id & 7;
  int rest = id >> 3;
  int mslot = rest & 15;
  int g = (rest >> 4) * 8 + xcd;
  int e = g / 11;
  int n0 = (g - e * 11) * 128;
  int cnt = counts[e];
  int m0 = mslot * 128;
  if (m0 >= cnt) return;

  short* As = (short*)smem;            // 128*32
  short* Bg = (short*)smem + 4096;
  short* Bu = (short*)smem + 8192;
  int* toks = (int*)(smem + 24576);

  if (tid < 128) {
    int r = m0 + tid;
    toks[tid] = tok_list[e * NTOK + (r < cnt ? r : cnt - 1)] & 0xFFFF;
  }
  __syncthreads();

  int sr = tid >> 1;             // 0..127
  int h = tid & 1;
  int key = (sr >> 1) & 3;
  int pair = ((2 * h) ^ key) >> 1;           // which 32B global block
  int sw = (key & 1) * 8;                    // swap c0/c1 on write
  const short* gA = xb + (size_t)toks[sr] * HIDDEN + pair * 16;
  // chunk-slab B base: logical chunk c0 = 2*pair of row n0+sr
  size_t ebase = (size_t)e * (HIDDEN * INTER);
  size_t boff = (size_t)(2 * pair) * (INTER * 8) + (size_t)(n0 + sr) * 8;
  const short* gGb = wgT + ebase + boff;
  const short* gUb = wuT + ebase + boff;
  short* wA0 = &As[sr * 32 + h * 16 + sw];
  short* wA1 = &As[sr * 32 + h * 16 + (8 - sw)];
  short* wG0 = &Bg[sr * 32 + h * 16 + sw];
  short* wG1 = &Bg[sr * 32 + h * 16 + (8 - sw)];
  short* wU0 = &Bu[sr * 32 + h * 16 + sw];
  short* wU1 = &Bu[sr * 32 + h * 16 + (8 - sw)];

  int wv = tid >> 6, lane = tid & 63;
  int wm = wv & 1, wn = wv >> 1;
  int q = lane >> 4, ml = lane & 15;
  int chk = q ^ ((ml >> 1) & 3);
  const short* ard = &As[(wm * 64 + ml) * 32 + chk * 8];
  const short* grd = &Bg[(wn * 64 + ml) * 32 + chk * 8];
  const short* urd = &Bu[(wn * 64 + ml) * 32 + chk * 8];

  f32x4 accg[4][4], accu[4][4];
#pragma unroll
  for (int i = 0; i < 4; ++i)
#pragma unroll
    for (int j = 0; j < 4; ++j) { accg[i][j] = (f32x4)0.f; accu[i][j] = (f32x4)0.f; }

  s16x8 a0 = *(const s16x8*)(gA);     s16x8 a1 = *(const s16x8*)(gA + 8);
  s16x8 g0 = *(const s16x8*)(gGb);    s16x8 g1 = *(const s16x8*)(gGb + INTER * 8);
  s16x8 u0 = *(const s16x8*)(gUb);    s16x8 u1 = *(const s16x8*)(gUb + INTER * 8);

  for (int k0 = 0; k0 < HIDDEN; k0 += 32) {
    __syncthreads();
    *(s16x8*)wA0 = a0; *(s16x8*)wA1 = a1;
    *(s16x8*)wG0 = g0; *(s16x8*)wG1 = g1;
    *(s16x8*)wU0 = u0; *(s16x8*)wU1 = u1;
    __syncthreads();

    int kn = (k0 + 32) & (HIDDEN - 1);
    size_t kboff = (size_t)(kn >> 5) * (4 * INTER * 8);
    a0 = *(const s16x8*)(gA + kn);         a1 = *(const s16x8*)(gA + kn + 8);
    g0 = *(const s16x8*)(gGb + kboff);     g1 = *(const s16x8*)(gGb + kboff + INTER * 8);
    u0 = *(const s16x8*)(gUb + kboff);     u1 = *(const s16x8*)(gUb + kboff + INTER * 8);

    s16x8 af[4], gf[4], uf[4];
#pragma unroll
    for (int i = 0; i < 4; ++i) af[i] = *(const s16x8*)(ard + i * 16 * 32);
#pragma unroll
    for (int j = 0; j < 4; ++j) {
      gf[j] = *(const s16x8*)(grd + j * 16 * 32);
      uf[j] = *(const s16x8*)(urd + j * 16 * 32);
    }
#pragma unroll
    for (int i = 0; i < 4; ++i)
#pragma unroll
      for (int j = 0; j < 4; ++j) {
        accg[i][j] = __builtin_amdgcn_mfma_f32_16x16x32_bf16(af[i], gf[j], accg[i][j], 0, 0, 0);
        accu[i][j] = __builtin_amdgcn_mfma_f32_16x16x32_bf16(af[i], uf[j], accu[i][j], 0, 0, 0);
      }
  }

  int hb = base[e];
#pragma unroll
  for (int i = 0; i < 4; ++i)
#pragma unroll
    for (int ii = 0; ii < 4; ++ii) {
      int r = m0 + wm * 64 + i * 16 + q * 4 + ii;
      if (r < cnt) {
        short* hp = hbuf + (size_t)(hb + r) * INTER + n0 + wn * 64 + ml;
#pragma unroll
        for (int j = 0; j < 4; ++j) {
          float gg = accg[i][j][ii], uu = accu[i][j][ii];
          float hh = (gg / (1.f + __expf(-gg))) * uu;
          hp[j * 16] = f2b(hh);
        }
      }
    }
}

// ---------------------------------------------------------------------------
// Phase B: Y = H @ Wd, K-split x2; scaled partials to ybuf[slot*2+ks][token]
// with plain stores (no atomics).
// ---------------------------------------------------------------------------
__global__ __launch_bounds__(256, 3) void down_mfma(
    const short* __restrict__ hbuf, const short* __restrict__ wdT,
    const int* __restrict__ counts, const int* __restrict__ base,
    const int* __restrict__ tok_list, const float* __restrict__ w_list,
    float* __restrict__ ybuf)
{
  // grid = 8 xcd * 16 m * 16 g-hi = 2048; g = (e,ks,n) in 0..127
  int id = blockIdx.x;
  int xcd = id & 7;
  int rest = id >> 3;
  int mslot = rest & 15;
  int g = (rest >> 4) * 8 + xcd;
  int e = g >> 4;
  int ks = (g >> 3) & 1;
  int n0 = (g & 7) * 128;
  int cnt = counts[e];
  int m0 = mslot * 128;
  if (m0 >= cnt) return;

  __shared__ short As[128 * 32];
  __shared__ short Bs[128 * 32];

  int tid = threadIdx.x;
  int hb = base[e];
  int kbeg = ks * KSPLIT_LEN, kend = kbeg + KSPLIT_LEN;

  int sr = tid >> 1;
  int h = tid & 1;
  int key = (sr >> 1) & 3;
  int pair = ((2 * h) ^ key) >> 1;
  int sw = (key & 1) * 8;
  int ra = m0 + sr; if (ra >= cnt) ra = cnt - 1;
  const short* gA = hbuf + (size_t)(hb + ra) * INTER + pair * 16;
  size_t ebase = (size_t)e * (HIDDEN * INTER);
  const short* gBb = wdT + ebase + (size_t)(2 * pair) * (HIDDEN * 8)
                         + (size_t)(n0 + sr) * 8;
  short* wA0 = &As[sr * 32 + h * 16 + sw];
  short* wA1 = &As[sr * 32 + h * 16 + (8 - sw)];
  short* wB0 = &Bs[sr * 32 + h * 16 + sw];
  short* wB1 = &Bs[sr * 32 + h * 16 + (8 - sw)];

  int wv = tid >> 6, lane = tid & 63;
  int wm = wv & 1, wn = wv >> 1;
  int q = lane >> 4, ml = lane & 15;
  int chk = q ^ ((ml >> 1) & 3);
  const short* ard = &As[(wm * 64 + ml) * 32 + chk * 8];
  const short* brd = &Bs[(wn * 64 + ml) * 32 + chk * 8];

  f32x4 acc[4][4];
#pragma unroll
  for (int i = 0; i < 4; ++i)
#pragma unroll
    for (int j = 0; j < 4; ++j) acc[i][j] = (f32x4)0.f;

  size_t kboff0 = (size_t)(kbeg >> 5) * (4 * HIDDEN * 8);
  s16x8 a0 = *(const s16x8*)(gA + kbeg);  s16x8 a1 = *(const s16x8*)(gA + kbeg + 8);
  s16x8 b0 = *(const s16x8*)(gBb + kboff0);
  s16x8 b1 = *(const s16x8*)(gBb + kboff0 + HIDDEN * 8);

  for (int k0 = kbeg; k0 < kend; k0 += 32) {
    __syncthreads();
    *(s16x8*)wA0 = a0; *(s16x8*)wA1 = a1;
    *(s16x8*)wB0 = b0; *(s16x8*)wB1 = b1;
    __syncthreads();

    int kn = k0 + 32; if (kn >= kend) kn = kbeg;
    size_t kboff = (size_t)(kn >> 5) * (4 * HIDDEN * 8);
    a0 = *(const s16x8*)(gA + kn);  a1 = *(const s16x8*)(gA + kn + 8);
    b0 = *(const s16x8*)(gBb + kboff);
    b1 = *(const s16x8*)(gBb + kboff + HIDDEN * 8);

    s16x8 af[4], bf[4];
#pragma unroll
    for (int i = 0; i < 4; ++i) af[i] = *(const s16x8*)(ard + i * 16 * 32);
#pragma unroll
    for (int j = 0; j < 4; ++j) bf[j] = *(const s16x8*)(brd + j * 16 * 32);
#pragma unroll
    for (int i = 0; i < 4; ++i)
#pragma unroll
      for (int j = 0; j < 4; ++j)
        acc[i][j] = __builtin_amdgcn_mfma_f32_16x16x32_bf16(af[i], bf[j], acc[i][j], 0, 0, 0);
  }

#pragma unroll
  for (int i = 0; i < 4; ++i)
#pragma unroll
    for (int ii = 0; ii < 4; ++ii) {
      int r = m0 + wm * 64 + i * 16 + q * 4 + ii;
      if (r < cnt) {
        int ent = tok_list[e * NTOK + r];
        int tok = ent & 0xFFFF, slot = ent >> 16;
        float wgt = w_list[e * NTOK + r];
        float* yp = ybuf + ((size_t)(slot * 2 + ks) * NTOK + tok) * HIDDEN
                    + n0 + wn * 64 + ml;
#pragma unroll
        for (int j = 0; j < 4; ++j)
          yp[j * 16] = acc[i][j][ii] * wgt;
      }
    }
}

// ---------------------------------------------------------------------------
// out = sum of 4 ybuf slabs (every element written -> no out memset needed)
// ---------------------------------------------------------------------------
__global__ __launch_bounds__(256) void combine_kernel(
    const float* __restrict__ ybuf, float* __restrict__ out)
{
  size_t i = (size_t)blockIdx.x * 256 + threadIdx.x;
  const size_t S = (size_t)NTOK * HIDDEN / 4;
  float4 a = ((const float4*)ybuf)[i];
  float4 b = ((const float4*)ybuf)[i + S];
  float4 c = ((const float4*)ybuf)[i + 2 * S];
  float4 d = ((const float4*)ybuf)[i + 3 * S];
  float4 o;
  o.x = (a.x + b.x) + (c.x + d.x);
  o.y = (a.y + b.y) + (c.y + d.y);
  o.z = (a.z + b.z) + (c.z + d.z);
  o.w = (a.w + b.w) + (c.w + d.w);
  ((float4*)out)[i] = o;
}

// ---------------------------------------------------------------------------
// ws layout (bytes):
//   0..32           counts[8]
//   32..64          base[8]
//   64..65600       tok_list[8][2048]  (token | slot<<16)
//   65600..131136   w_list[8][2048]
//   131136..139328  ce[2048]
//   139328..155712  cw[2048] float2
//   155712          xb   bf16 [2048][1024]      (4 MB)
//   +4 MB           wgT  bf16 slabs             (23.07 MB) } ybuf[4] (32 MB
//   +23.07 MB       wuT  bf16 slabs             (23.07 MB) } fp32) aliases
//                                                          } wgT+wuT after
//                                                          } gateup completes
//   +23.07 MB       wdT  bf16 slabs
//   +23.07 MB       hbuf bf16 [4096][1408]      (11.5 MB)
//   total ~85.2 MB
// ---------------------------------------------------------------------------
extern "C" void kernel_launch(void* const* d_in, const int* in_sizes, int n_in,
                              void* d_out, int out_size, void* d_ws, size_t ws_size,
                              hipStream_t stream)
{
  const float* x  = (const float*)d_in[0];
  const float* rw = (const float*)d_in[1];
  const float* wg = (const float*)d_in[2];
  const float* wu = (const float*)d_in[3];
  const float* wd = (const float*)d_in[4];
  float* out = (float*)d_out;

  char* ws = (char*)d_ws;
  int*    counts   = (int*)(ws);
  int*    base     = (int*)(ws + 32);
  int*    tok_list = (int*)(ws + 64);
  float*  w_list   = (float*)(ws + 64 + NEXP * NTOK * 4);
  size_t off = 64 + 2 * (size_t)NEXP * NTOK * 4;
  int*    ce = (int*)(ws + off);     off += NTOK * 4;
  float2* cw = (float2*)(ws + off);  off += NTOK * 8;
  short* xb  = (short*)(ws + off);  off += (size_t)NTOK * HIDDEN * 2;
  short* wgT = (short*)(ws + off);  off += (size_t)NEXP * HIDDEN * INTER * 2;
  short* wuT = (short*)(ws + off);  off += (size_t)NEXP * HIDDEN * INTER * 2;
  short* wdT = (short*)(ws + off);  off += (size_t)NEXP * HIDDEN * INTER * 2;
  short* hbuf = (short*)(ws + off);
  float* ybuf = (float*)wgT;   // wgT+wuT dead after gateup; 32 MB fits in 46 MB

  router_wconv_gu<<<512 + 2816, 256, 0, stream>>>(x, rw, wg, wu, ce, cw, xb, wgT, wuT);
  build_lists<<<NEXP, 256, 0, stream>>>(ce, cw, counts, base, tok_list, w_list);

  gateup_wconv_d<<<1408 + 1408, 256, 0, stream>>>(
      xb, wgT, wuT, wd, wdT, counts, base, tok_list, hbuf);

  down_mfma<<<8 * 16 * 16, 256, 0, stream>>>(hbuf, wdT, counts, base, tok_list, w_list, ybuf);

  combine_kernel<<<(NTOK * HIDDEN / 4) / 256, 256, 0, stream>>>(ybuf, out);
}